// Round 1
// baseline (582.454 us; speedup 1.0000x reference)
//
#include <hip/hip_runtime.h>
#include <math.h>

#define CB 16
#define CL 2048
#define CD 512
#define CE 8
#define CH 8
#define CEH 64
#define CF 2048

// ws layout (float offsets)
#define WS_GATES 0
#define WS_XN    (WS_GATES + CB*CE)
#define WS_QH    (WS_XN + CB*CD)
#define WS_SBIAS (WS_QH + CB*CE*CD)
#define WS_WK    (WS_SBIAS + CB*CE*CH)
#define WS_SC    (WS_WK + CB*CEH*CD)
#define WS_LMAX  (WS_SC + CB*CL*CEH)
#define WS_LSUM  (WS_LMAX + CB*8*CEH)
#define WS_RMAX  (WS_LSUM + CB*8*CEH)
#define WS_RINV  (WS_RMAX + CB*CEH)
#define WS_ENT   (WS_RINV + CB*CEH)
#define WS_REFF  (WS_ENT + CB*CE*8)
#define WS_ATTN  (WS_REFF + CB*CEH*CD)
#define WS_X     (WS_ATTN + CB*CE*CD)
#define WS_XO    (WS_X + CB*CE*CD)
#define WS_HB    (WS_XO + CB*CE*CD)

__global__ __launch_bounds__(256) void k1_gates_xn(
    const float* __restrict__ q, const float* __restrict__ wg,
    float* __restrict__ xn, float* __restrict__ gates) {
  int b = blockIdx.x, t = threadIdx.x;
  __shared__ float red[256];
  __shared__ float logits[CE];
  float v0 = q[b*CD + t], v1 = q[b*CD + 256 + t];
  red[t] = v0 + v1; __syncthreads();
  for (int s = 128; s > 0; s >>= 1) { if (t < s) red[t] += red[t+s]; __syncthreads(); }
  float mu = red[0] * (1.0f/CD); __syncthreads();
  float c0 = v0 - mu, c1 = v1 - mu;
  red[t] = c0*c0 + c1*c1; __syncthreads();
  for (int s = 128; s > 0; s >>= 1) { if (t < s) red[t] += red[t+s]; __syncthreads(); }
  float rstd = rsqrtf(red[0] * (1.0f/CD) + 1e-5f); __syncthreads();
  xn[b*CD + t] = c0 * rstd;
  xn[b*CD + 256 + t] = c1 * rstd;
  float ge[CE];
  #pragma unroll
  for (int e = 0; e < CE; e++) ge[e] = v0 * wg[t*CE + e] + v1 * wg[(256+t)*CE + e];
  for (int e = 0; e < CE; e++) {
    red[t] = ge[e]; __syncthreads();
    for (int s = 128; s > 0; s >>= 1) { if (t < s) red[t] += red[t+s]; __syncthreads(); }
    if (t == 0) logits[e] = red[0];
    __syncthreads();
  }
  if (t == 0) {
    float m = logits[0];
    for (int e = 1; e < CE; e++) m = fmaxf(m, logits[e]);
    float s = 0.f, ex[CE];
    for (int e = 0; e < CE; e++) { ex[e] = __expf(logits[e] - m); s += ex[e]; }
    for (int e = 0; e < CE; e++) gates[b*CE + e] = ex[e] / s;
  }
}

__global__ __launch_bounds__(256) void k2_qh(
    const float* __restrict__ xn, const float* __restrict__ g,
    const float* __restrict__ bln, const float* __restrict__ Wq,
    const float* __restrict__ bq, float* __restrict__ qh) {
  int e = blockIdx.y, k0 = blockIdx.x * 64, t = threadIdx.x;
  __shared__ float qn[CB][CD];
  for (int idx = t; idx < CB*CD; idx += 256) {
    int d = idx & 511;
    qn[idx >> 9][d] = xn[idx] * g[e*CD + d] + bln[e*CD + d];
  }
  __syncthreads();
  int k = k0 + (t & 63), bg = (t >> 6) * 4;
  const float* W = Wq + (size_t)e*CD*CD + k;
  float a0=0,a1=0,a2=0,a3=0;
  #pragma unroll 4
  for (int d = 0; d < CD; d++) {
    float w = W[(size_t)d*CD];
    a0 += qn[bg+0][d]*w; a1 += qn[bg+1][d]*w; a2 += qn[bg+2][d]*w; a3 += qn[bg+3][d]*w;
  }
  float bb = bq[e*CD + k];
  qh[((bg+0)*CE + e)*CD + k] = a0 + bb;
  qh[((bg+1)*CE + e)*CD + k] = a1 + bb;
  qh[((bg+2)*CE + e)*CD + k] = a2 + bb;
  qh[((bg+3)*CE + e)*CD + k] = a3 + bb;
}

__global__ __launch_bounds__(64) void k3_sbias(
    const float* __restrict__ qh, const float* __restrict__ bk,
    float* __restrict__ sbias) {
  int be = blockIdx.x, b = be >> 3, e = be & 7, t = threadIdx.x;
  for (int h = 0; h < CH; h++) {
    float v = qh[(b*CE + e)*CD + h*64 + t] * bk[e*CD + h*64 + t];
    for (int off = 32; off > 0; off >>= 1) v += __shfl_down(v, off);
    if (t == 0) sbias[(b*CE + e)*CH + h] = v;
  }
}

__global__ __launch_bounds__(256) void k4_wkeff(
    const float* __restrict__ Wk, const float* __restrict__ qh,
    float* __restrict__ wk) {
  int e = blockIdx.y, d0 = blockIdx.x * 64, t = threadIdx.x;
  __shared__ float wks[64][65];
  __shared__ float qhs[CB][64];
  int d = t & 63, bg = (t >> 6) * 4;
  for (int h = 0; h < CH; h++) {
    for (int idx = t; idx < 64*64; idx += 256) {
      int c = idx & 63, dd = idx >> 6;
      wks[dd][c] = Wk[(size_t)e*CD*CD + (size_t)(d0+dd)*CD + h*64 + c];
    }
    for (int idx = t; idx < CB*64; idx += 256) {
      int c = idx & 63, bb = idx >> 6;
      qhs[bb][c] = qh[(bb*CE + e)*CD + h*64 + c];
    }
    __syncthreads();
    float a0=0,a1=0,a2=0,a3=0;
    #pragma unroll 8
    for (int c = 0; c < 64; c++) {
      float w = wks[d][c];
      a0 += qhs[bg+0][c]*w; a1 += qhs[bg+1][c]*w; a2 += qhs[bg+2][c]*w; a3 += qhs[bg+3][c]*w;
    }
    int eh = e*8 + h;
    wk[((size_t)((bg+0)*CEH + eh))*CD + d0 + d] = a0;
    wk[((size_t)((bg+1)*CEH + eh))*CD + d0 + d] = a1;
    wk[((size_t)((bg+2)*CEH + eh))*CD + d0 + d] = a2;
    wk[((size_t)((bg+3)*CEH + eh))*CD + d0 + d] = a3;
    __syncthreads();
  }
}

__global__ __launch_bounds__(256) void k5_scores(
    const float* __restrict__ ret, const float* __restrict__ wk,
    const float* __restrict__ sbias, float* __restrict__ sc) {
  int b = blockIdx.y, l0 = blockIdx.x * 64, t = threadIdx.x;
  __shared__ __align__(16) float As[32][68];
  __shared__ __align__(16) float Ws[32][68];
  int ti = t & 15, tj = t >> 4;
  float acc[4][4] = {};
  const float* retb = ret + (size_t)b*CL*CD;
  const float* wkb  = wk  + (size_t)b*CEH*CD;
  for (int d0 = 0; d0 < CD; d0 += 32) {
    #pragma unroll
    for (int p = 0; p < 8; p++) {
      int idx = p*256 + t, d = idx & 31, l = idx >> 5;
      As[d][l] = retb[(size_t)(l0 + l)*CD + d0 + d];
    }
    #pragma unroll
    for (int p = 0; p < 8; p++) {
      int idx = p*256 + t, d = idx & 31, eh = idx >> 5;
      Ws[d][eh] = wkb[(size_t)eh*CD + d0 + d];
    }
    __syncthreads();
    #pragma unroll
    for (int d = 0; d < 32; d++) {
      float4 av = *reinterpret_cast<const float4*>(&As[d][tj*4]);
      float4 wv = *reinterpret_cast<const float4*>(&Ws[d][ti*4]);
      float av4[4] = {av.x, av.y, av.z, av.w};
      float wv4[4] = {wv.x, wv.y, wv.z, wv.w};
      #pragma unroll
      for (int i = 0; i < 4; i++)
        #pragma unroll
        for (int j = 0; j < 4; j++)
          acc[i][j] += wv4[i]*av4[j];
    }
    __syncthreads();
  }
  float sb[4];
  #pragma unroll
  for (int i = 0; i < 4; i++) {
    int eh = ti*4 + i;
    sb[i] = sbias[(b*CE + (eh >> 3))*CH + (eh & 7)] * 0.125f;
  }
  #pragma unroll
  for (int j = 0; j < 4; j++) {
    int l = l0 + tj*4 + j;
    float4 o;
    o.x = acc[0][j]*0.125f + sb[0];
    o.y = acc[1][j]*0.125f + sb[1];
    o.z = acc[2][j]*0.125f + sb[2];
    o.w = acc[3][j]*0.125f + sb[3];
    *reinterpret_cast<float4*>(&sc[((size_t)(b*CL + l))*CEH + ti*4]) = o;
  }
}

__global__ __launch_bounds__(256) void k5s_stats(
    const float* __restrict__ sc, float* __restrict__ lmax, float* __restrict__ lsum) {
  int b = blockIdx.y, lc = blockIdx.x, t = threadIdx.x;
  int eh = t & 63, ls = t >> 6, l0 = lc * 256;
  float m = -1e30f, s = 0.f;
  for (int l = l0 + ls; l < l0 + 256; l += 4) {
    float x = sc[((size_t)(b*CL + l))*CEH + eh];
    float nm = fmaxf(m, x);
    s = s * __expf(m - nm) + __expf(x - nm);
    m = nm;
  }
  __shared__ float sm[4][64], ss[4][64];
  sm[ls][eh] = m; ss[ls][eh] = s;
  __syncthreads();
  if (ls == 0) {
    float M = sm[0][eh];
    for (int i = 1; i < 4; i++) M = fmaxf(M, sm[i][eh]);
    float S = 0.f;
    for (int i = 0; i < 4; i++) S += ss[i][eh] * __expf(sm[i][eh] - M);
    lmax[(size_t)(b*8 + lc)*CEH + eh] = M;
    lsum[(size_t)(b*8 + lc)*CEH + eh] = S;
  }
}

__global__ __launch_bounds__(64) void k5b_row(
    const float* __restrict__ lmax, const float* __restrict__ lsum,
    float* __restrict__ rmax, float* __restrict__ rinv) {
  int b = blockIdx.x, eh = threadIdx.x;
  float M = -1e30f;
  for (int c = 0; c < 8; c++) M = fmaxf(M, lmax[(b*8 + c)*CEH + eh]);
  float S = 0.f;
  for (int c = 0; c < 8; c++) S += lsum[(b*8 + c)*CEH + eh] * __expf(lmax[(b*8 + c)*CEH + eh] - M);
  rmax[b*CEH + eh] = M;
  rinv[b*CEH + eh] = 1.f / S;
}

__global__ __launch_bounds__(256) void k5c_norm_ent(
    float* __restrict__ sc, const float* __restrict__ rmax,
    const float* __restrict__ rinv, float* __restrict__ entp) {
  int b = blockIdx.y, lc = blockIdx.x, t = threadIdx.x;
  int eh = t & 63, ls = t >> 6, l0 = lc * 256;
  float M = rmax[b*CEH + eh], inv = rinv[b*CEH + eh];
  float ent = 0.f;
  for (int l = l0 + ls; l < l0 + 256; l += 4) {
    size_t ix = ((size_t)(b*CL + l))*CEH + eh;
    float p = __expf(sc[ix] - M) * inv;
    sc[ix] = p;
    float ps = p;
    ps += __shfl_xor(ps, 1);
    ps += __shfl_xor(ps, 2);
    ps += __shfl_xor(ps, 4);
    if ((eh & 7) == 0) {
      float pb = fmaxf(ps * 0.125f, 1e-12f);
      ent -= pb * logf(pb);
    }
  }
  __shared__ float es[4][8];
  if ((eh & 7) == 0) es[ls][eh >> 3] = ent;
  __syncthreads();
  if (t < 8) {
    entp[(b*CE + t)*8 + lc] = es[0][t] + es[1][t] + es[2][t] + es[3][t];
  }
}

__global__ __launch_bounds__(256) void k6_reff(
    const float* __restrict__ sc, const float* __restrict__ ret,
    float* __restrict__ reff) {
  int b = blockIdx.y, d0 = blockIdx.x * 32, t = threadIdx.x;
  __shared__ __align__(16) float Ps[32][68];
  __shared__ __align__(16) float Rs[32][36];
  int di = t & 7, ej = t >> 3;
  float acc[2][4] = {};
  const float* scb  = sc  + (size_t)b*CL*CEH;
  const float* retb = ret + (size_t)b*CL*CD + d0;
  for (int l0 = 0; l0 < CL; l0 += 32) {
    #pragma unroll
    for (int p = 0; p < 8; p++) {
      int idx = p*256 + t, eh = idx & 63, l = idx >> 6;
      Ps[l][eh] = scb[(size_t)(l0 + l)*CEH + eh];
    }
    #pragma unroll
    for (int p = 0; p < 4; p++) {
      int idx = p*256 + t, d = idx & 31, l = idx >> 5;
      Rs[l][d] = retb[(size_t)(l0 + l)*CD + d];
    }
    __syncthreads();
    #pragma unroll
    for (int l = 0; l < 32; l++) {
      float4 rv = *reinterpret_cast<const float4*>(&Rs[l][di*4]);
      float2 pv = *reinterpret_cast<const float2*>(&Ps[l][ej*2]);
      float rv4[4] = {rv.x, rv.y, rv.z, rv.w};
      #pragma unroll
      for (int i = 0; i < 4; i++) {
        acc[0][i] += pv.x * rv4[i];
        acc[1][i] += pv.y * rv4[i];
      }
    }
    __syncthreads();
  }
  #pragma unroll
  for (int j = 0; j < 2; j++) {
    int eh = ej*2 + j;
    float4 o = {acc[j][0], acc[j][1], acc[j][2], acc[j][3]};
    *reinterpret_cast<float4*>(&reff[((size_t)(b*CEH + eh))*CD + d0 + di*4]) = o;
  }
}

__global__ __launch_bounds__(256) void k6b_attn(
    const float* __restrict__ reff, const float* __restrict__ Wv,
    const float* __restrict__ bv, float* __restrict__ attn) {
  int e = blockIdx.y, h = blockIdx.x, t = threadIdx.x;
  int eh = e*8 + h;
  __shared__ float rs[CB][CD];
  for (int idx = t; idx < CB*CD; idx += 256) {
    rs[idx >> 9][idx & 511] = reff[((size_t)((idx >> 9)*CEH + eh))*CD + (idx & 511)];
  }
  __syncthreads();
  int c = t & 63, bg = (t >> 6) * 4;
  const float* W = Wv + (size_t)e*CD*CD + h*64 + c;
  float a0=0,a1=0,a2=0,a3=0;
  #pragma unroll 4
  for (int d = 0; d < CD; d++) {
    float w = W[(size_t)d*CD];
    a0 += rs[bg+0][d]*w; a1 += rs[bg+1][d]*w; a2 += rs[bg+2][d]*w; a3 += rs[bg+3][d]*w;
  }
  float bb = bv[e*CD + h*64 + c];
  attn[((bg+0)*CE + e)*CD + h*64 + c] = a0 + bb;
  attn[((bg+1)*CE + e)*CD + h*64 + c] = a1 + bb;
  attn[((bg+2)*CE + e)*CD + h*64 + c] = a2 + bb;
  attn[((bg+3)*CE + e)*CD + h*64 + c] = a3 + bb;
}

__global__ __launch_bounds__(256) void k6c_attnout(
    const float* __restrict__ attn, const float* __restrict__ Wo,
    const float* __restrict__ bo, const float* __restrict__ q,
    float* __restrict__ x) {
  int e = blockIdx.y, k0 = blockIdx.x * 64, t = threadIdx.x;
  __shared__ float as_[CB][CD];
  for (int idx = t; idx < CB*CD; idx += 256) {
    as_[idx >> 9][idx & 511] = attn[((idx >> 9)*CE + e)*CD + (idx & 511)];
  }
  __syncthreads();
  int k = k0 + (t & 63), bg = (t >> 6) * 4;
  const float* W = Wo + (size_t)e*CD*CD + k;
  float a0=0,a1=0,a2=0,a3=0;
  #pragma unroll 4
  for (int d = 0; d < CD; d++) {
    float w = W[(size_t)d*CD];
    a0 += as_[bg+0][d]*w; a1 += as_[bg+1][d]*w; a2 += as_[bg+2][d]*w; a3 += as_[bg+3][d]*w;
  }
  float bb = bo[e*CD + k];
  x[((bg+0)*CE + e)*CD + k] = q[(bg+0)*CD + k] + a0 + bb;
  x[((bg+1)*CE + e)*CD + k] = q[(bg+1)*CD + k] + a1 + bb;
  x[((bg+2)*CE + e)*CD + k] = q[(bg+2)*CD + k] + a2 + bb;
  x[((bg+3)*CE + e)*CD + k] = q[(bg+3)*CD + k] + a3 + bb;
}

__global__ __launch_bounds__(256) void k7_lno(
    const float* __restrict__ x, const float* __restrict__ g,
    const float* __restrict__ bb, float* __restrict__ xo) {
  int be = blockIdx.x, e = be & 7, t = threadIdx.x;
  __shared__ float red[256];
  const float* xr = x + (size_t)be*CD;
  float v0 = xr[t], v1 = xr[256 + t];
  red[t] = v0 + v1; __syncthreads();
  for (int s = 128; s > 0; s >>= 1) { if (t < s) red[t] += red[t+s]; __syncthreads(); }
  float mu = red[0] * (1.0f/CD); __syncthreads();
  float c0 = v0 - mu, c1 = v1 - mu;
  red[t] = c0*c0 + c1*c1; __syncthreads();
  for (int s = 128; s > 0; s >>= 1) { if (t < s) red[t] += red[t+s]; __syncthreads(); }
  float rstd = rsqrtf(red[0] * (1.0f/CD) + 1e-5f);
  xo[be*CD + t]       = c0*rstd*g[e*CD + t]       + bb[e*CD + t];
  xo[be*CD + 256 + t] = c1*rstd*g[e*CD + 256 + t] + bb[e*CD + 256 + t];
}

__global__ __launch_bounds__(256) void k8_ffn1(
    const float* __restrict__ xo, const float* __restrict__ W1,
    const float* __restrict__ b1, float* __restrict__ hb) {
  int e = blockIdx.y, f0 = blockIdx.x * 128, t = threadIdx.x;
  __shared__ float xs[CB][CD];
  for (int idx = t; idx < CB*CD; idx += 256) {
    xs[idx >> 9][idx & 511] = xo[((idx >> 9)*CE + e)*CD + (idx & 511)];
  }
  __syncthreads();
  int f = f0 + (t & 127), bg = (t >> 7) * 8;
  const float* W = W1 + (size_t)e*CD*CF + f;
  float acc[8] = {};
  #pragma unroll 2
  for (int d = 0; d < CD; d++) {
    float w = W[(size_t)d*CF];
    #pragma unroll
    for (int i = 0; i < 8; i++) acc[i] += xs[bg+i][d]*w;
  }
  float bb1 = b1[e*CF + f];
  #pragma unroll
  for (int i = 0; i < 8; i++) {
    float v = acc[i] + bb1;
    hb[((size_t)((bg+i)*CE + e))*CF + f] = 0.5f*v*(1.f + erff(v*0.70710678118f));
  }
}

__global__ __launch_bounds__(256) void k9_ffn2(
    const float* __restrict__ hb, const float* __restrict__ W2,
    const float* __restrict__ b2, const float* __restrict__ x,
    float* __restrict__ yout) {
  int e = blockIdx.y, d0 = blockIdx.x * 32, t = threadIdx.x;
  __shared__ float hs[CB][513];
  int d = d0 + (t & 31), bg = (t >> 5) * 2;
  float a0 = 0.f, a1 = 0.f;
  for (int fc = 0; fc < CF; fc += 512) {
    for (int idx = t; idx < CB*512; idx += 256) {
      hs[idx >> 9][idx & 511] = hb[((size_t)((idx >> 9)*CE + e))*CF + fc + (idx & 511)];
    }
    __syncthreads();
    const float* W = W2 + (size_t)e*CF*CD + (size_t)fc*CD + d;
    #pragma unroll 4
    for (int f = 0; f < 512; f++) {
      float w = W[(size_t)f*CD];
      a0 += hs[bg+0][f]*w;
      a1 += hs[bg+1][f]*w;
    }
    __syncthreads();
  }
  float bb2 = b2[e*CD + d];
  int r0 = ((bg+0)*CE + e)*CD + d, r1 = ((bg+1)*CE + e)*CD + d;
  yout[r0] = a0 + bb2 + x[r0];
  yout[r1] = a1 + bb2 + x[r1];
}

__global__ __launch_bounds__(512) void k10_final(
    const float* __restrict__ gates, const float* __restrict__ entp,
    const float* __restrict__ yout, float* __restrict__ fused,
    float* __restrict__ gtout) {
  int b = blockIdx.x, t = threadIdx.x;
  __shared__ float gt_s[CE];
  if (t < CE) {
    float Hs = 0.f;
    for (int c = 0; c < 8; c++) Hs += entp[(b*CE + t)*8 + c];
    gt_s[t] = gates[b*CE + t] * __expf(-0.5f * Hs);
  }
  __syncthreads();
  if (t == 0) {
    float s = 0.f;
    for (int e = 0; e < CE; e++) s += gt_s[e];
    s += 1e-9f;
    for (int e = 0; e < CE; e++) { gt_s[e] /= s; gtout[b*CE + e] = gt_s[e]; }
  }
  __syncthreads();
  float acc = 0.f;
  #pragma unroll
  for (int e = 0; e < CE; e++) acc += gt_s[e] * yout[(b*CE + e)*CD + t];
  fused[b*CD + t] = acc;  // ALPHA = 1.0 -> fused == mixture
}

extern "C" void kernel_launch(void* const* d_in, const int* in_sizes, int n_in,
                              void* d_out, int out_size, void* d_ws, size_t ws_size,
                              hipStream_t stream) {
  const float* q    = (const float*)d_in[0];
  const float* ret  = (const float*)d_in[1];
  const float* wg   = (const float*)d_in[2];
  const float* lnqg = (const float*)d_in[3];
  const float* lnqb = (const float*)d_in[4];
  const float* Wq   = (const float*)d_in[5];
  const float* bq   = (const float*)d_in[6];
  const float* Wk   = (const float*)d_in[7];
  const float* bk   = (const float*)d_in[8];
  const float* Wv   = (const float*)d_in[9];
  const float* bv   = (const float*)d_in[10];
  const float* Wo   = (const float*)d_in[11];
  const float* bo   = (const float*)d_in[12];
  const float* lnog = (const float*)d_in[13];
  const float* lnob = (const float*)d_in[14];
  const float* W1   = (const float*)d_in[15];
  const float* b1   = (const float*)d_in[16];
  const float* W2   = (const float*)d_in[17];
  const float* b2   = (const float*)d_in[18];

  float* ws = (float*)d_ws;
  float* fused = (float*)d_out;
  float* yout  = fused + CB*CD;
  float* gtout = yout + CB*CE*CD;

  float* gates = ws + WS_GATES;
  float* xn    = ws + WS_XN;
  float* qh    = ws + WS_QH;
  float* sbias = ws + WS_SBIAS;
  float* wkeff = ws + WS_WK;
  float* sc    = ws + WS_SC;
  float* lmax  = ws + WS_LMAX;
  float* lsum  = ws + WS_LSUM;
  float* rmax  = ws + WS_RMAX;
  float* rinv  = ws + WS_RINV;
  float* entp  = ws + WS_ENT;
  float* reff  = ws + WS_REFF;
  float* attn  = ws + WS_ATTN;
  float* xb    = ws + WS_X;
  float* xo    = ws + WS_XO;
  float* hbuf  = ws + WS_HB;

  k1_gates_xn<<<CB, 256, 0, stream>>>(q, wg, xn, gates);
  k2_qh<<<dim3(8, CE), 256, 0, stream>>>(xn, lnqg, lnqb, Wq, bq, qh);
  k3_sbias<<<CB*CE, 64, 0, stream>>>(qh, bk, sbias);
  k4_wkeff<<<dim3(8, CE), 256, 0, stream>>>(Wk, qh, wkeff);
  k5_scores<<<dim3(32, CB), 256, 0, stream>>>(ret, wkeff, sbias, sc);
  k5s_stats<<<dim3(8, CB), 256, 0, stream>>>(sc, lmax, lsum);
  k5b_row<<<CB, 64, 0, stream>>>(lmax, lsum, rmax, rinv);
  k5c_norm_ent<<<dim3(8, CB), 256, 0, stream>>>(sc, rmax, rinv, entp);
  k6_reff<<<dim3(16, CB), 256, 0, stream>>>(sc, ret, reff);
  k6b_attn<<<dim3(CH, CE), 256, 0, stream>>>(reff, Wv, bv, attn);
  k6c_attnout<<<dim3(8, CE), 256, 0, stream>>>(attn, Wo, bo, q, xb);
  k7_lno<<<CB*CE, 256, 0, stream>>>(xb, lnog, lnob, xo);
  k8_ffn1<<<dim3(16, CE), 256, 0, stream>>>(xo, W1, b1, hbuf);
  k9_ffn2<<<dim3(16, CE), 256, 0, stream>>>(hbuf, W2, b2, xb, yout);
  k10_final<<<CB, 512, 0, stream>>>(gates, entp, yout, fused, gtout);
}

// Round 2
// 235.037 us; speedup vs baseline: 2.4781x; 2.4781x over previous
//
#include <hip/hip_runtime.h>
#include <math.h>

#define CB 16
#define CL 2048
#define CD 512
#define CE 8
#define CH 8
#define CEH 64
#define CF 2048

// ws layout (float offsets)
#define WS_GATES 0
#define WS_XN    (WS_GATES + CB*CE)
#define WS_QN    (WS_XN + CB*CD)
#define WS_QH    (WS_QN + CB*CE*CD)
#define WS_SBIAS (WS_QH + CB*CE*CD)
#define WS_WK    (WS_SBIAS + CB*CE*CH)
#define WS_SC    (WS_WK + CB*CEH*CD)
#define WS_PART  WS_SC   /* partial buffers alias sc: liveness is disjoint */
#define WS_LMAX  (WS_SC + CB*CL*CEH)
#define WS_LSUM  (WS_LMAX + CB*8*CEH)
#define WS_RMAX  (WS_LSUM + CB*8*CEH)
#define WS_RINV  (WS_RMAX + CB*CEH)
#define WS_ENT   (WS_RINV + CB*CEH)
#define WS_REFF  (WS_ENT + CB*CE*8)
#define WS_ATTN  (WS_REFF + CB*CEH*CD)
#define WS_X     (WS_ATTN + CB*CE*CD)
#define WS_XO    (WS_X + CB*CE*CD)
#define WS_HB    (WS_XO + CB*CE*CD)

__global__ __launch_bounds__(256) void k1_gates_xn(
    const float* __restrict__ q, const float* __restrict__ wg,
    float* __restrict__ xn, float* __restrict__ gates) {
  int b = blockIdx.x, t = threadIdx.x;
  __shared__ float red[256];
  __shared__ float logits[CE];
  float v0 = q[b*CD + t], v1 = q[b*CD + 256 + t];
  red[t] = v0 + v1; __syncthreads();
  for (int s = 128; s > 0; s >>= 1) { if (t < s) red[t] += red[t+s]; __syncthreads(); }
  float mu = red[0] * (1.0f/CD); __syncthreads();
  float c0 = v0 - mu, c1 = v1 - mu;
  red[t] = c0*c0 + c1*c1; __syncthreads();
  for (int s = 128; s > 0; s >>= 1) { if (t < s) red[t] += red[t+s]; __syncthreads(); }
  float rstd = rsqrtf(red[0] * (1.0f/CD) + 1e-5f); __syncthreads();
  xn[b*CD + t] = c0 * rstd;
  xn[b*CD + 256 + t] = c1 * rstd;
  float ge[CE];
  #pragma unroll
  for (int e = 0; e < CE; e++) ge[e] = v0 * wg[t*CE + e] + v1 * wg[(256+t)*CE + e];
  for (int e = 0; e < CE; e++) {
    red[t] = ge[e]; __syncthreads();
    for (int s = 128; s > 0; s >>= 1) { if (t < s) red[t] += red[t+s]; __syncthreads(); }
    if (t == 0) logits[e] = red[0];
    __syncthreads();
  }
  if (t == 0) {
    float m = logits[0];
    for (int e = 1; e < CE; e++) m = fmaxf(m, logits[e]);
    float s = 0.f, ex[CE];
    for (int e = 0; e < CE; e++) { ex[e] = __expf(logits[e] - m); s += ex[e]; }
    for (int e = 0; e < CE; e++) gates[b*CE + e] = ex[e] / s;
  }
}

__global__ __launch_bounds__(256) void k1b_qn(
    const float* __restrict__ xn, const float* __restrict__ g,
    const float* __restrict__ bln, float* __restrict__ qn) {
  int i = blockIdx.x*256 + threadIdx.x;      // flat [b][e][d], 65536
  int b = i >> 12, e = (i >> 9) & 7, d = i & 511;
  qn[i] = xn[b*CD + d] * g[e*CD + d] + bln[e*CD + d];
}

// Streaming split-K GEMV16: out_partial[kc][b][e][n] = sum_k X[b,e,k]*W[e,k,n]
template<int KC>
__global__ __launch_bounds__(256) void gstream(
    const float* __restrict__ X, int xb_, int xe_,
    const float* __restrict__ W, size_t we_, int ldw,
    float* __restrict__ P, int ntiles, size_t pc_, int pb_, int pe_) {
  int e = blockIdx.y;
  int nt = blockIdx.x % ntiles, kc = blockIdx.x / ntiles;
  int n0 = nt * 64, k0 = kc * KC;
  __shared__ float xs[KC][16];
  __shared__ float red[16][64];
  int t = threadIdx.x;
  for (int idx = t; idx < KC * 16; idx += 256) {
    int k = idx >> 4, b = idx & 15;
    xs[k][b] = X[(size_t)b * xb_ + (size_t)e * xe_ + k0 + k];
  }
  __syncthreads();
  int n = t & 63, kq = t >> 6;
  float acc[16] = {};
  const float* Wp = W + (size_t)e * we_ + (size_t)k0 * ldw + n0 + n;
  #pragma unroll 4
  for (int k = kq * (KC/4); k < (kq+1) * (KC/4); k++) {
    float w = Wp[(size_t)k * ldw];
    const float4* xp = reinterpret_cast<const float4*>(xs[k]);
    float4 x0 = xp[0], x1 = xp[1], x2 = xp[2], x3 = xp[3];
    acc[0]  += x0.x*w; acc[1]  += x0.y*w; acc[2]  += x0.z*w; acc[3]  += x0.w*w;
    acc[4]  += x1.x*w; acc[5]  += x1.y*w; acc[6]  += x1.z*w; acc[7]  += x1.w*w;
    acc[8]  += x2.x*w; acc[9]  += x2.y*w; acc[10] += x2.z*w; acc[11] += x2.w*w;
    acc[12] += x3.x*w; acc[13] += x3.y*w; acc[14] += x3.z*w; acc[15] += x3.w*w;
  }
  if (kq == 0) {
    #pragma unroll
    for (int b = 0; b < 16; b++) red[b][n] = acc[b];
  }
  __syncthreads();
  #pragma unroll
  for (int qq = 1; qq < 4; qq++) {
    if (kq == qq) {
      #pragma unroll
      for (int b = 0; b < 16; b++) red[b][n] += acc[b];
    }
    __syncthreads();
  }
  #pragma unroll
  for (int i = 0; i < 4; i++) {
    int b = kq*4 + i;
    P[(size_t)kc*pc_ + (size_t)b*pb_ + (size_t)e*pe_ + n0 + n] = red[b][n];
  }
}

// Wv variant: per (eh) block column h*64..h*64+63, split over d (K=512, 8 chunks)
__global__ __launch_bounds__(256) void gstream_v(
    const float* __restrict__ reff, const float* __restrict__ Wv,
    float* __restrict__ P) {
  int eh = blockIdx.y, kc = blockIdx.x;
  int e = eh >> 3, h = eh & 7;
  int k0 = kc * 64;
  __shared__ float xs[64][16];
  __shared__ float red[16][64];
  int t = threadIdx.x;
  for (int idx = t; idx < 64 * 16; idx += 256) {
    int k = idx >> 4, b = idx & 15;
    xs[k][b] = reff[((size_t)(b*CEH + eh))*CD + k0 + k];
  }
  __syncthreads();
  int n = t & 63, kq = t >> 6;
  float acc[16] = {};
  const float* Wp = Wv + (size_t)e*CD*CD + (size_t)k0*CD + h*64 + n;
  #pragma unroll 4
  for (int k = kq*16; k < kq*16 + 16; k++) {
    float w = Wp[(size_t)k * CD];
    const float4* xp = reinterpret_cast<const float4*>(xs[k]);
    float4 x0 = xp[0], x1 = xp[1], x2 = xp[2], x3 = xp[3];
    acc[0]  += x0.x*w; acc[1]  += x0.y*w; acc[2]  += x0.z*w; acc[3]  += x0.w*w;
    acc[4]  += x1.x*w; acc[5]  += x1.y*w; acc[6]  += x1.z*w; acc[7]  += x1.w*w;
    acc[8]  += x2.x*w; acc[9]  += x2.y*w; acc[10] += x2.z*w; acc[11] += x2.w*w;
    acc[12] += x3.x*w; acc[13] += x3.y*w; acc[14] += x3.z*w; acc[15] += x3.w*w;
  }
  if (kq == 0) { 
    #pragma unroll
    for (int b = 0; b < 16; b++) red[b][n] = acc[b]; }
  __syncthreads();
  #pragma unroll
  for (int qq = 1; qq < 4; qq++) {
    if (kq == qq) {
      #pragma unroll
      for (int b = 0; b < 16; b++) red[b][n] += acc[b];
    }
    __syncthreads();
  }
  #pragma unroll
  for (int i = 0; i < 4; i++) {
    int b = kq*4 + i;
    P[(size_t)kc*65536 + (size_t)b*4096 + (size_t)eh*64 + n] = red[b][n];
  }
}

__global__ __launch_bounds__(256) void comb8_bias(
    const float* __restrict__ P, const float* __restrict__ bias,
    float* __restrict__ out) {
  int i = blockIdx.x*256 + threadIdx.x;
  float s = bias[i & 4095];
  #pragma unroll
  for (int c = 0; c < 8; c++) s += P[(size_t)c*65536 + i];
  out[i] = s;
}

__global__ __launch_bounds__(256) void comb8_o(
    const float* __restrict__ P, const float* __restrict__ bias,
    const float* __restrict__ q, float* __restrict__ x) {
  int i = blockIdx.x*256 + threadIdx.x;
  float s = bias[i & 4095] + q[(i >> 12)*CD + (i & 511)];
  #pragma unroll
  for (int c = 0; c < 8; c++) s += P[(size_t)c*65536 + i];
  x[i] = s;
}

__global__ __launch_bounds__(256) void comb4_gelu(
    const float* __restrict__ P, const float* __restrict__ bias,
    float* __restrict__ out) {
  int i = blockIdx.x*256 + threadIdx.x;   // flat [b][e][f], 262144
  float s = bias[i & 16383];
  #pragma unroll
  for (int c = 0; c < 4; c++) s += P[(size_t)c*262144 + i];
  out[i] = 0.5f*s*(1.f + erff(s*0.70710678118f));
}

__global__ __launch_bounds__(256) void comb8_ffn2(
    const float* __restrict__ P, const float* __restrict__ bias,
    const float* __restrict__ x, float* __restrict__ yout) {
  int i = blockIdx.x*256 + threadIdx.x;
  float s = bias[i & 4095] + x[i];
  #pragma unroll
  for (int c = 0; c < 8; c++) s += P[(size_t)c*65536 + i];
  yout[i] = s;
}

__global__ __launch_bounds__(64) void k3_sbias(
    const float* __restrict__ qh, const float* __restrict__ bk,
    float* __restrict__ sbias) {
  int be = blockIdx.x, b = be >> 3, e = be & 7, t = threadIdx.x;
  for (int h = 0; h < CH; h++) {
    float v = qh[(b*CE + e)*CD + h*64 + t] * bk[e*CD + h*64 + t];
    for (int off = 32; off > 0; off >>= 1) v += __shfl_down(v, off);
    if (t == 0) sbias[(b*CE + e)*CH + h] = v;
  }
}

__global__ __launch_bounds__(256) void k4_wkeff(
    const float* __restrict__ Wk, const float* __restrict__ qh,
    float* __restrict__ wk) {
  int e = blockIdx.y;
  int h = blockIdx.x >> 3, dt = blockIdx.x & 7;
  int d0 = dt * 64;
  __shared__ float wks[64][65];   // [c][d]
  __shared__ float qs[64][16];    // [c][b]
  __shared__ float red[16][64];
  int t = threadIdx.x;
  for (int idx = t; idx < 64*64; idx += 256) {
    int c = idx & 63, d = idx >> 6;
    wks[c][d] = Wk[(size_t)e*CD*CD + (size_t)(d0+d)*CD + h*64 + c];
  }
  for (int idx = t; idx < 64*16; idx += 256) {
    int c = idx >> 4, b = idx & 15;
    qs[c][b] = qh[(b*CE + e)*CD + h*64 + c];
  }
  __syncthreads();
  int d = t & 63, cq = t >> 6;
  float acc[16] = {};
  #pragma unroll 4
  for (int c = cq*16; c < cq*16 + 16; c++) {
    float w = wks[c][d];
    const float4* xp = reinterpret_cast<const float4*>(qs[c]);
    float4 x0 = xp[0], x1 = xp[1], x2 = xp[2], x3 = xp[3];
    acc[0]  += x0.x*w; acc[1]  += x0.y*w; acc[2]  += x0.z*w; acc[3]  += x0.w*w;
    acc[4]  += x1.x*w; acc[5]  += x1.y*w; acc[6]  += x1.z*w; acc[7]  += x1.w*w;
    acc[8]  += x2.x*w; acc[9]  += x2.y*w; acc[10] += x2.z*w; acc[11] += x2.w*w;
    acc[12] += x3.x*w; acc[13] += x3.y*w; acc[14] += x3.z*w; acc[15] += x3.w*w;
  }
  if (cq == 0) { 
    #pragma unroll
    for (int b = 0; b < 16; b++) red[b][d] = acc[b]; }
  __syncthreads();
  #pragma unroll
  for (int qq = 1; qq < 4; qq++) {
    if (cq == qq) {
      #pragma unroll
      for (int b = 0; b < 16; b++) red[b][d] += acc[b];
    }
    __syncthreads();
  }
  int eh = e*8 + h;
  #pragma unroll
  for (int i = 0; i < 4; i++) {
    int b = cq*4 + i;
    wk[((size_t)(b*CEH + eh))*CD + d0 + d] = red[b][d];
  }
}

__global__ __launch_bounds__(256) void k5_scores(
    const float* __restrict__ ret, const float* __restrict__ wk,
    const float* __restrict__ sbias, float* __restrict__ sc) {
  int b = blockIdx.y, l0 = blockIdx.x * 64, t = threadIdx.x;
  __shared__ __align__(16) float As[32][68];
  __shared__ __align__(16) float Ws[32][68];
  int ti = t & 15, tj = t >> 4;
  float acc[4][4] = {};
  const float* retb = ret + (size_t)b*CL*CD;
  const float* wkb  = wk  + (size_t)b*CEH*CD;
  for (int d0 = 0; d0 < CD; d0 += 32) {
    #pragma unroll
    for (int p = 0; p < 8; p++) {
      int idx = p*256 + t, d = idx & 31, l = idx >> 5;
      As[d][l] = retb[(size_t)(l0 + l)*CD + d0 + d];
    }
    #pragma unroll
    for (int p = 0; p < 8; p++) {
      int idx = p*256 + t, d = idx & 31, eh = idx >> 5;
      Ws[d][eh] = wkb[(size_t)eh*CD + d0 + d];
    }
    __syncthreads();
    #pragma unroll
    for (int d = 0; d < 32; d++) {
      float4 av = *reinterpret_cast<const float4*>(&As[d][tj*4]);
      float4 wv = *reinterpret_cast<const float4*>(&Ws[d][ti*4]);
      float av4[4] = {av.x, av.y, av.z, av.w};
      float wv4[4] = {wv.x, wv.y, wv.z, wv.w};
      #pragma unroll
      for (int i = 0; i < 4; i++)
        #pragma unroll
        for (int j = 0; j < 4; j++)
          acc[i][j] += wv4[i]*av4[j];
    }
    __syncthreads();
  }
  float sb[4];
  #pragma unroll
  for (int i = 0; i < 4; i++) {
    int eh = ti*4 + i;
    sb[i] = sbias[(b*CE + (eh >> 3))*CH + (eh & 7)] * 0.125f;
  }
  #pragma unroll
  for (int j = 0; j < 4; j++) {
    int l = l0 + tj*4 + j;
    float4 o;
    o.x = acc[0][j]*0.125f + sb[0];
    o.y = acc[1][j]*0.125f + sb[1];
    o.z = acc[2][j]*0.125f + sb[2];
    o.w = acc[3][j]*0.125f + sb[3];
    *reinterpret_cast<float4*>(&sc[((size_t)(b*CL + l))*CEH + ti*4]) = o;
  }
}

__global__ __launch_bounds__(256) void k5s_stats(
    const float* __restrict__ sc, float* __restrict__ lmax, float* __restrict__ lsum) {
  int b = blockIdx.y, lc = blockIdx.x, t = threadIdx.x;
  int eh = t & 63, ls = t >> 6, l0 = lc * 256;
  float m = -1e30f, s = 0.f;
  for (int l = l0 + ls; l < l0 + 256; l += 4) {
    float x = sc[((size_t)(b*CL + l))*CEH + eh];
    float nm = fmaxf(m, x);
    s = s * __expf(m - nm) + __expf(x - nm);
    m = nm;
  }
  __shared__ float sm[4][64], ss[4][64];
  sm[ls][eh] = m; ss[ls][eh] = s;
  __syncthreads();
  if (ls == 0) {
    float M = sm[0][eh];
    for (int i = 1; i < 4; i++) M = fmaxf(M, sm[i][eh]);
    float S = 0.f;
    for (int i = 0; i < 4; i++) S += ss[i][eh] * __expf(sm[i][eh] - M);
    lmax[(size_t)(b*8 + lc)*CEH + eh] = M;
    lsum[(size_t)(b*8 + lc)*CEH + eh] = S;
  }
}

__global__ __launch_bounds__(64) void k5b_row(
    const float* __restrict__ lmax, const float* __restrict__ lsum,
    float* __restrict__ rmax, float* __restrict__ rinv) {
  int b = blockIdx.x, eh = threadIdx.x;
  float M = -1e30f;
  for (int c = 0; c < 8; c++) M = fmaxf(M, lmax[(b*8 + c)*CEH + eh]);
  float S = 0.f;
  for (int c = 0; c < 8; c++) S += lsum[(b*8 + c)*CEH + eh] * __expf(lmax[(b*8 + c)*CEH + eh] - M);
  rmax[b*CEH + eh] = M;
  rinv[b*CEH + eh] = 1.f / S;
}

__global__ __launch_bounds__(256) void k5c_norm_ent(
    float* __restrict__ sc, const float* __restrict__ rmax,
    const float* __restrict__ rinv, float* __restrict__ entp) {
  int b = blockIdx.y, lc = blockIdx.x, t = threadIdx.x;
  int eh = t & 63, ls = t >> 6, l0 = lc * 256;
  float M = rmax[b*CEH + eh], inv = rinv[b*CEH + eh];
  float ent = 0.f;
  for (int l = l0 + ls; l < l0 + 256; l += 4) {
    size_t ix = ((size_t)(b*CL + l))*CEH + eh;
    float p = __expf(sc[ix] - M) * inv;
    sc[ix] = p;
    float ps = p;
    ps += __shfl_xor(ps, 1);
    ps += __shfl_xor(ps, 2);
    ps += __shfl_xor(ps, 4);
    if ((eh & 7) == 0) {
      float pb = fmaxf(ps * 0.125f, 1e-12f);
      ent -= pb * logf(pb);
    }
  }
  __shared__ float es[4][8];
  if ((eh & 7) == 0) es[ls][eh >> 3] = ent;
  __syncthreads();
  if (t < 8) {
    entp[(b*CE + t)*8 + lc] = es[0][t] + es[1][t] + es[2][t] + es[3][t];
  }
}

__global__ __launch_bounds__(256) void k6_reff(
    const float* __restrict__ sc, const float* __restrict__ ret,
    float* __restrict__ reff) {
  int b = blockIdx.y, d0 = blockIdx.x * 32, t = threadIdx.x;
  __shared__ __align__(16) float Ps[32][68];
  __shared__ __align__(16) float Rs[32][36];
  int di = t & 7, ej = t >> 3;
  float acc[2][4] = {};
  const float* scb  = sc  + (size_t)b*CL*CEH;
  const float* retb = ret + (size_t)b*CL*CD + d0;
  for (int l0 = 0; l0 < CL; l0 += 32) {
    #pragma unroll
    for (int p = 0; p < 8; p++) {
      int idx = p*256 + t, eh = idx & 63, l = idx >> 6;
      Ps[l][eh] = scb[(size_t)(l0 + l)*CEH + eh];
    }
    #pragma unroll
    for (int p = 0; p < 4; p++) {
      int idx = p*256 + t, d = idx & 31, l = idx >> 5;
      Rs[l][d] = retb[(size_t)(l0 + l)*CD + d];
    }
    __syncthreads();
    #pragma unroll
    for (int l = 0; l < 32; l++) {
      float4 rv = *reinterpret_cast<const float4*>(&Rs[l][di*4]);
      float2 pv = *reinterpret_cast<const float2*>(&Ps[l][ej*2]);
      float rv4[4] = {rv.x, rv.y, rv.z, rv.w};
      #pragma unroll
      for (int i = 0; i < 4; i++) {
        acc[0][i] += pv.x * rv4[i];
        acc[1][i] += pv.y * rv4[i];
      }
    }
    __syncthreads();
  }
  #pragma unroll
  for (int j = 0; j < 2; j++) {
    int eh = ej*2 + j;
    float4 o = {acc[j][0], acc[j][1], acc[j][2], acc[j][3]};
    *reinterpret_cast<float4*>(&reff[((size_t)(b*CEH + eh))*CD + d0 + di*4]) = o;
  }
}

__global__ __launch_bounds__(256) void k7_lno(
    const float* __restrict__ x, const float* __restrict__ g,
    const float* __restrict__ bb, float* __restrict__ xo) {
  int be = blockIdx.x, e = be & 7, t = threadIdx.x;
  __shared__ float red[256];
  const float* xr = x + (size_t)be*CD;
  float v0 = xr[t], v1 = xr[256 + t];
  red[t] = v0 + v1; __syncthreads();
  for (int s = 128; s > 0; s >>= 1) { if (t < s) red[t] += red[t+s]; __syncthreads(); }
  float mu = red[0] * (1.0f/CD); __syncthreads();
  float c0 = v0 - mu, c1 = v1 - mu;
  red[t] = c0*c0 + c1*c1; __syncthreads();
  for (int s = 128; s > 0; s >>= 1) { if (t < s) red[t] += red[t+s]; __syncthreads(); }
  float rstd = rsqrtf(red[0] * (1.0f/CD) + 1e-5f);
  xo[be*CD + t]       = c0*rstd*g[e*CD + t]       + bb[e*CD + t];
  xo[be*CD + 256 + t] = c1*rstd*g[e*CD + 256 + t] + bb[e*CD + 256 + t];
}

__global__ __launch_bounds__(512) void k10_final(
    const float* __restrict__ gates, const float* __restrict__ entp,
    const float* __restrict__ yout, float* __restrict__ fused,
    float* __restrict__ gtout) {
  int b = blockIdx.x, t = threadIdx.x;
  __shared__ float gt_s[CE];
  if (t < CE) {
    float Hs = 0.f;
    for (int c = 0; c < 8; c++) Hs += entp[(b*CE + t)*8 + c];
    gt_s[t] = gates[b*CE + t] * __expf(-0.5f * Hs);
  }
  __syncthreads();
  if (t == 0) {
    float s = 0.f;
    for (int e = 0; e < CE; e++) s += gt_s[e];
    s += 1e-9f;
    for (int e = 0; e < CE; e++) { gt_s[e] /= s; gtout[b*CE + e] = gt_s[e]; }
  }
  __syncthreads();
  float acc = 0.f;
  #pragma unroll
  for (int e = 0; e < CE; e++) acc += gt_s[e] * yout[(b*CE + e)*CD + t];
  fused[b*CD + t] = acc;  // ALPHA = 1.0 -> fused == mixture
}

extern "C" void kernel_launch(void* const* d_in, const int* in_sizes, int n_in,
                              void* d_out, int out_size, void* d_ws, size_t ws_size,
                              hipStream_t stream) {
  const float* q    = (const float*)d_in[0];
  const float* ret  = (const float*)d_in[1];
  const float* wg   = (const float*)d_in[2];
  const float* lnqg = (const float*)d_in[3];
  const float* lnqb = (const float*)d_in[4];
  const float* Wq   = (const float*)d_in[5];
  const float* bq   = (const float*)d_in[6];
  const float* Wk   = (const float*)d_in[7];
  const float* bk   = (const float*)d_in[8];
  const float* Wv   = (const float*)d_in[9];
  const float* bv   = (const float*)d_in[10];
  const float* Wo   = (const float*)d_in[11];
  const float* bo   = (const float*)d_in[12];
  const float* lnog = (const float*)d_in[13];
  const float* lnob = (const float*)d_in[14];
  const float* W1   = (const float*)d_in[15];
  const float* b1   = (const float*)d_in[16];
  const float* W2   = (const float*)d_in[17];
  const float* b2   = (const float*)d_in[18];

  float* ws = (float*)d_ws;
  float* fused = (float*)d_out;
  float* yout  = fused + CB*CD;
  float* gtout = yout + CB*CE*CD;

  float* gates = ws + WS_GATES;
  float* xn    = ws + WS_XN;
  float* qn    = ws + WS_QN;
  float* qh    = ws + WS_QH;
  float* sbias = ws + WS_SBIAS;
  float* wkeff = ws + WS_WK;
  float* sc    = ws + WS_SC;
  float* part  = ws + WS_PART;
  float* lmax  = ws + WS_LMAX;
  float* lsum  = ws + WS_LSUM;
  float* rmax  = ws + WS_RMAX;
  float* rinv  = ws + WS_RINV;
  float* entp  = ws + WS_ENT;
  float* reff  = ws + WS_REFF;
  float* attn  = ws + WS_ATTN;
  float* xb    = ws + WS_X;
  float* xo    = ws + WS_XO;
  float* hbuf  = ws + WS_HB;

  k1_gates_xn<<<CB, 256, 0, stream>>>(q, wg, xn, gates);
  k1b_qn<<<256, 256, 0, stream>>>(xn, lnqg, lnqb, qn);
  // qh = qn @ Wq + bq : K=512 (8 chunks of 64), N=512 (8 tiles)
  gstream<64><<<dim3(64, CE), 256, 0, stream>>>(qn, CE*CD, CD, Wq, (size_t)CD*CD, CD,
                                                part, 8, 65536, CE*CD, CD);
  comb8_bias<<<256, 256, 0, stream>>>(part, bq, qh);
  k3_sbias<<<CB*CE, 64, 0, stream>>>(qh, bk, sbias);
  k4_wkeff<<<dim3(64, CE), 256, 0, stream>>>(Wk, qh, wkeff);
  k5_scores<<<dim3(32, CB), 256, 0, stream>>>(ret, wkeff, sbias, sc);
  k5s_stats<<<dim3(8, CB), 256, 0, stream>>>(sc, lmax, lsum);
  k5b_row<<<CB, 64, 0, stream>>>(lmax, lsum, rmax, rinv);
  k5c_norm_ent<<<dim3(8, CB), 256, 0, stream>>>(sc, rmax, rinv, entp);
  k6_reff<<<dim3(16, CB), 256, 0, stream>>>(sc, ret, reff);
  // attn = reff @ Wv + bv : per (e,h), K=512 (8 chunks)
  gstream_v<<<dim3(8, CEH), 256, 0, stream>>>(reff, Wv, part);
  comb8_bias<<<256, 256, 0, stream>>>(part, bv, attn);
  // x = q + attn @ Wo + bo
  gstream<64><<<dim3(64, CE), 256, 0, stream>>>(attn, CE*CD, CD, Wo, (size_t)CD*CD, CD,
                                                part, 8, 65536, CE*CD, CD);
  comb8_o<<<256, 256, 0, stream>>>(part, bo, q, xb);
  k7_lno<<<CB*CE, 256, 0, stream>>>(xb, lnog, lnob, xo);
  // h = gelu(xo @ W1 + b1) : K=512 (4 chunks of 128), N=2048 (32 tiles)
  gstream<128><<<dim3(128, CE), 256, 0, stream>>>(xo, CE*CD, CD, W1, (size_t)CD*CF, CF,
                                                  part, 32, 262144, CE*CF, CF);
  comb4_gelu<<<1024, 256, 0, stream>>>(part, b1, hbuf);
  // y = h @ W2 + b2 + x : K=2048 (8 chunks of 256), N=512 (8 tiles)
  gstream<256><<<dim3(64, CE), 256, 0, stream>>>(hbuf, CE*CF, CF, W2, (size_t)CF*CD, CD,
                                                 part, 8, 65536, CE*CD, CD);
  comb8_ffn2<<<256, 256, 0, stream>>>(part, b2, xb, yout);
  k10_final<<<CB, 512, 0, stream>>>(gates, entp, yout, fused, gtout);
}

// Round 3
// 197.501 us; speedup vs baseline: 2.9491x; 1.1901x over previous
//
#include <hip/hip_runtime.h>
#include <math.h>

#define CB 16
#define CL 2048
#define CD 512
#define CE 8
#define CH 8
#define CEH 64
#define CF 2048

// ws layout (float offsets)
#define WS_GATES 0
#define WS_XN    (WS_GATES + CB*CE)
#define WS_QN    (WS_XN + CB*CD)
#define WS_QH    (WS_QN + CB*CE*CD)
#define WS_SBIAS (WS_QH + CB*CE*CD)
#define WS_WK    (WS_SBIAS + CB*CE*CH)
#define WS_SC    (WS_WK + CB*CEH*CD)
#define WS_PART  WS_SC   /* gstream partial buffers alias sc: liveness is disjoint */
#define WS_LMAX  (WS_SC + CB*CL*CEH)
#define WS_LSUM  (WS_LMAX + CB*8*CEH)
#define WS_RMAX  (WS_LSUM + CB*8*CEH)
#define WS_RINV  (WS_RMAX + CB*CEH)
#define WS_ENT   (WS_RINV + CB*CEH)
#define WS_REFF  (WS_ENT + CB*CE*8)
#define WS_ATTN  (WS_REFF + CB*CEH*CD)
#define WS_X     (WS_ATTN + CB*CE*CD)
#define WS_XO    (WS_X + CB*CE*CD)
#define WS_HB    (WS_XO + CB*CE*CD)
#define WS_RP    (WS_HB + CB*CE*CF)   /* 3 * CB*CEH*CD fp32 partials for k6 */

__global__ __launch_bounds__(256) void k1_gates_xn(
    const float* __restrict__ q, const float* __restrict__ wg,
    float* __restrict__ xn, float* __restrict__ gates) {
  int b = blockIdx.x, t = threadIdx.x;
  __shared__ float red[256];
  __shared__ float logits[CE];
  float v0 = q[b*CD + t], v1 = q[b*CD + 256 + t];
  red[t] = v0 + v1; __syncthreads();
  for (int s = 128; s > 0; s >>= 1) { if (t < s) red[t] += red[t+s]; __syncthreads(); }
  float mu = red[0] * (1.0f/CD); __syncthreads();
  float c0 = v0 - mu, c1 = v1 - mu;
  red[t] = c0*c0 + c1*c1; __syncthreads();
  for (int s = 128; s > 0; s >>= 1) { if (t < s) red[t] += red[t+s]; __syncthreads(); }
  float rstd = rsqrtf(red[0] * (1.0f/CD) + 1e-5f); __syncthreads();
  xn[b*CD + t] = c0 * rstd;
  xn[b*CD + 256 + t] = c1 * rstd;
  float ge[CE];
  #pragma unroll
  for (int e = 0; e < CE; e++) ge[e] = v0 * wg[t*CE + e] + v1 * wg[(256+t)*CE + e];
  for (int e = 0; e < CE; e++) {
    red[t] = ge[e]; __syncthreads();
    for (int s = 128; s > 0; s >>= 1) { if (t < s) red[t] += red[t+s]; __syncthreads(); }
    if (t == 0) logits[e] = red[0];
    __syncthreads();
  }
  if (t == 0) {
    float m = logits[0];
    for (int e = 1; e < CE; e++) m = fmaxf(m, logits[e]);
    float s = 0.f, ex[CE];
    for (int e = 0; e < CE; e++) { ex[e] = __expf(logits[e] - m); s += ex[e]; }
    for (int e = 0; e < CE; e++) gates[b*CE + e] = ex[e] / s;
  }
}

__global__ __launch_bounds__(256) void k1b_qn(
    const float* __restrict__ xn, const float* __restrict__ g,
    const float* __restrict__ bln, float* __restrict__ qn) {
  int i = blockIdx.x*256 + threadIdx.x;      // flat [b][e][d], 65536
  int b = i >> 12, e = (i >> 9) & 7, d = i & 511;
  qn[i] = xn[b*CD + d] * g[e*CD + d] + bln[e*CD + d];
}

// Streaming split-K GEMV16: out_partial[kc][b][e][n] = sum_k X[b,e,k]*W[e,k,n]
template<int KC>
__global__ __launch_bounds__(256) void gstream(
    const float* __restrict__ X, int xb_, int xe_,
    const float* __restrict__ W, size_t we_, int ldw,
    float* __restrict__ P, int ntiles, size_t pc_, int pb_, int pe_) {
  int e = blockIdx.y;
  int nt = blockIdx.x % ntiles, kc = blockIdx.x / ntiles;
  int n0 = nt * 64, k0 = kc * KC;
  __shared__ float xs[KC][16];
  __shared__ float red[16][64];
  int t = threadIdx.x;
  for (int idx = t; idx < KC * 16; idx += 256) {
    int k = idx >> 4, b = idx & 15;
    xs[k][b] = X[(size_t)b * xb_ + (size_t)e * xe_ + k0 + k];
  }
  __syncthreads();
  int n = t & 63, kq = t >> 6;
  float acc[16] = {};
  const float* Wp = W + (size_t)e * we_ + (size_t)k0 * ldw + n0 + n;
  #pragma unroll 4
  for (int k = kq * (KC/4); k < (kq+1) * (KC/4); k++) {
    float w = Wp[(size_t)k * ldw];
    const float4* xp = reinterpret_cast<const float4*>(xs[k]);
    float4 x0 = xp[0], x1 = xp[1], x2 = xp[2], x3 = xp[3];
    acc[0]  += x0.x*w; acc[1]  += x0.y*w; acc[2]  += x0.z*w; acc[3]  += x0.w*w;
    acc[4]  += x1.x*w; acc[5]  += x1.y*w; acc[6]  += x1.z*w; acc[7]  += x1.w*w;
    acc[8]  += x2.x*w; acc[9]  += x2.y*w; acc[10] += x2.z*w; acc[11] += x2.w*w;
    acc[12] += x3.x*w; acc[13] += x3.y*w; acc[14] += x3.z*w; acc[15] += x3.w*w;
  }
  if (kq == 0) {
    #pragma unroll
    for (int b = 0; b < 16; b++) red[b][n] = acc[b];
  }
  __syncthreads();
  #pragma unroll
  for (int qq = 1; qq < 4; qq++) {
    if (kq == qq) {
      #pragma unroll
      for (int b = 0; b < 16; b++) red[b][n] += acc[b];
    }
    __syncthreads();
  }
  #pragma unroll
  for (int i = 0; i < 4; i++) {
    int b = kq*4 + i;
    P[(size_t)kc*pc_ + (size_t)b*pb_ + (size_t)e*pe_ + n0 + n] = red[b][n];
  }
}

// Wv variant: per (eh) block column h*64..h*64+63, split over d (K=512, 8 chunks)
__global__ __launch_bounds__(256) void gstream_v(
    const float* __restrict__ reff, const float* __restrict__ Wv,
    float* __restrict__ P) {
  int eh = blockIdx.y, kc = blockIdx.x;
  int e = eh >> 3, h = eh & 7;
  int k0 = kc * 64;
  __shared__ float xs[64][16];
  __shared__ float red[16][64];
  int t = threadIdx.x;
  for (int idx = t; idx < 64 * 16; idx += 256) {
    int k = idx >> 4, b = idx & 15;
    xs[k][b] = reff[((size_t)(b*CEH + eh))*CD + k0 + k];
  }
  __syncthreads();
  int n = t & 63, kq = t >> 6;
  float acc[16] = {};
  const float* Wp = Wv + (size_t)e*CD*CD + (size_t)k0*CD + h*64 + n;
  #pragma unroll 4
  for (int k = kq*16; k < kq*16 + 16; k++) {
    float w = Wp[(size_t)k * CD];
    const float4* xp = reinterpret_cast<const float4*>(xs[k]);
    float4 x0 = xp[0], x1 = xp[1], x2 = xp[2], x3 = xp[3];
    acc[0]  += x0.x*w; acc[1]  += x0.y*w; acc[2]  += x0.z*w; acc[3]  += x0.w*w;
    acc[4]  += x1.x*w; acc[5]  += x1.y*w; acc[6]  += x1.z*w; acc[7]  += x1.w*w;
    acc[8]  += x2.x*w; acc[9]  += x2.y*w; acc[10] += x2.z*w; acc[11] += x2.w*w;
    acc[12] += x3.x*w; acc[13] += x3.y*w; acc[14] += x3.z*w; acc[15] += x3.w*w;
  }
  if (kq == 0) { 
    #pragma unroll
    for (int b = 0; b < 16; b++) red[b][n] = acc[b]; }
  __syncthreads();
  #pragma unroll
  for (int qq = 1; qq < 4; qq++) {
    if (kq == qq) {
      #pragma unroll
      for (int b = 0; b < 16; b++) red[b][n] += acc[b];
    }
    __syncthreads();
  }
  #pragma unroll
  for (int i = 0; i < 4; i++) {
    int b = kq*4 + i;
    P[(size_t)kc*65536 + (size_t)b*4096 + (size_t)eh*64 + n] = red[b][n];
  }
}

__global__ __launch_bounds__(256) void comb8_bias(
    const float* __restrict__ P, const float* __restrict__ bias,
    float* __restrict__ out) {
  int i = blockIdx.x*256 + threadIdx.x;
  float s = bias[i & 4095];
  #pragma unroll
  for (int c = 0; c < 8; c++) s += P[(size_t)c*65536 + i];
  out[i] = s;
}

__global__ __launch_bounds__(256) void comb8_o(
    const float* __restrict__ P, const float* __restrict__ bias,
    const float* __restrict__ q, float* __restrict__ x) {
  int i = blockIdx.x*256 + threadIdx.x;
  float s = bias[i & 4095] + q[(i >> 12)*CD + (i & 511)];
  #pragma unroll
  for (int c = 0; c < 8; c++) s += P[(size_t)c*65536 + i];
  x[i] = s;
}

__global__ __launch_bounds__(256) void comb4_gelu(
    const float* __restrict__ P, const float* __restrict__ bias,
    float* __restrict__ out) {
  int i = blockIdx.x*256 + threadIdx.x;   // flat [b][e][f], 262144
  float s = bias[i & 16383];
  #pragma unroll
  for (int c = 0; c < 4; c++) s += P[(size_t)c*262144 + i];
  out[i] = 0.5f*s*(1.f + erff(s*0.70710678118f));
}

__global__ __launch_bounds__(256) void comb8_ffn2(
    const float* __restrict__ P, const float* __restrict__ bias,
    const float* __restrict__ x, float* __restrict__ yout) {
  int i = blockIdx.x*256 + threadIdx.x;
  float s = bias[i & 4095] + x[i];
  #pragma unroll
  for (int c = 0; c < 8; c++) s += P[(size_t)c*65536 + i];
  yout[i] = s;
}

__global__ __launch_bounds__(64) void k3_sbias(
    const float* __restrict__ qh, const float* __restrict__ bk,
    float* __restrict__ sbias) {
  int be = blockIdx.x, b = be >> 3, e = be & 7, t = threadIdx.x;
  for (int h = 0; h < CH; h++) {
    float v = qh[(b*CE + e)*CD + h*64 + t] * bk[e*CD + h*64 + t];
    for (int off = 32; off > 0; off >>= 1) v += __shfl_down(v, off);
    if (t == 0) sbias[(b*CE + e)*CH + h] = v;
  }
}

__global__ __launch_bounds__(256) void k4_wkeff(
    const float* __restrict__ Wk, const float* __restrict__ qh,
    float* __restrict__ wk) {
  int e = blockIdx.y;
  int h = blockIdx.x >> 3, dt = blockIdx.x & 7;
  int d0 = dt * 64;
  __shared__ float wks[64][65];   // [c][d]
  __shared__ float qs[64][16];    // [c][b]
  __shared__ float red[16][64];
  int t = threadIdx.x;
  for (int idx = t; idx < 64*64; idx += 256) {
    int c = idx & 63, d = idx >> 6;
    wks[c][d] = Wk[(size_t)e*CD*CD + (size_t)(d0+d)*CD + h*64 + c];
  }
  for (int idx = t; idx < 64*16; idx += 256) {
    int c = idx >> 4, b = idx & 15;
    qs[c][b] = qh[(b*CE + e)*CD + h*64 + c];
  }
  __syncthreads();
  int d = t & 63, cq = t >> 6;
  float acc[16] = {};
  #pragma unroll 4
  for (int c = cq*16; c < cq*16 + 16; c++) {
    float w = wks[c][d];
    const float4* xp = reinterpret_cast<const float4*>(qs[c]);
    float4 x0 = xp[0], x1 = xp[1], x2 = xp[2], x3 = xp[3];
    acc[0]  += x0.x*w; acc[1]  += x0.y*w; acc[2]  += x0.z*w; acc[3]  += x0.w*w;
    acc[4]  += x1.x*w; acc[5]  += x1.y*w; acc[6]  += x1.z*w; acc[7]  += x1.w*w;
    acc[8]  += x2.x*w; acc[9]  += x2.y*w; acc[10] += x2.z*w; acc[11] += x2.w*w;
    acc[12] += x3.x*w; acc[13] += x3.y*w; acc[14] += x3.z*w; acc[15] += x3.w*w;
  }
  if (cq == 0) { 
    #pragma unroll
    for (int b = 0; b < 16; b++) red[b][d] = acc[b]; }
  __syncthreads();
  #pragma unroll
  for (int qq = 1; qq < 4; qq++) {
    if (cq == qq) {
      #pragma unroll
      for (int b = 0; b < 16; b++) red[b][d] += acc[b];
    }
    __syncthreads();
  }
  int eh = e*8 + h;
  #pragma unroll
  for (int i = 0; i < 4; i++) {
    int b = cq*4 + i;
    wk[((size_t)(b*CEH + eh))*CD + d0 + d] = red[b][d];
  }
}

__global__ __launch_bounds__(256) void k5_scores(
    const float* __restrict__ ret, const float* __restrict__ wk,
    const float* __restrict__ sbias, float* __restrict__ sc) {
  int b = blockIdx.y, l0 = blockIdx.x * 64, t = threadIdx.x;
  __shared__ __align__(16) float As[32][68];
  __shared__ __align__(16) float Ws[32][68];
  int ti = t & 15, tj = t >> 4;
  float acc[4][4] = {};
  const float* retb = ret + (size_t)b*CL*CD;
  const float* wkb  = wk  + (size_t)b*CEH*CD;
  for (int d0 = 0; d0 < CD; d0 += 32) {
    #pragma unroll
    for (int p = 0; p < 8; p++) {
      int idx = p*256 + t, d = idx & 31, l = idx >> 5;
      As[d][l] = retb[(size_t)(l0 + l)*CD + d0 + d];
    }
    #pragma unroll
    for (int p = 0; p < 8; p++) {
      int idx = p*256 + t, d = idx & 31, eh = idx >> 5;
      Ws[d][eh] = wkb[(size_t)eh*CD + d0 + d];
    }
    __syncthreads();
    #pragma unroll
    for (int d = 0; d < 32; d++) {
      float4 av = *reinterpret_cast<const float4*>(&As[d][tj*4]);
      float4 wv = *reinterpret_cast<const float4*>(&Ws[d][ti*4]);
      float av4[4] = {av.x, av.y, av.z, av.w};
      float wv4[4] = {wv.x, wv.y, wv.z, wv.w};
      #pragma unroll
      for (int i = 0; i < 4; i++)
        #pragma unroll
        for (int j = 0; j < 4; j++)
          acc[i][j] += wv4[i]*av4[j];
    }
    __syncthreads();
  }
  float sb[4];
  #pragma unroll
  for (int i = 0; i < 4; i++) {
    int eh = ti*4 + i;
    sb[i] = sbias[(b*CE + (eh >> 3))*CH + (eh & 7)] * 0.125f;
  }
  #pragma unroll
  for (int j = 0; j < 4; j++) {
    int l = l0 + tj*4 + j;
    float4 o;
    o.x = acc[0][j]*0.125f + sb[0];
    o.y = acc[1][j]*0.125f + sb[1];
    o.z = acc[2][j]*0.125f + sb[2];
    o.w = acc[3][j]*0.125f + sb[3];
    *reinterpret_cast<float4*>(&sc[((size_t)(b*CL + l))*CEH + ti*4]) = o;
  }
}

__global__ __launch_bounds__(256) void k5s_stats(
    const float* __restrict__ sc, float* __restrict__ lmax, float* __restrict__ lsum) {
  int b = blockIdx.y, lc = blockIdx.x, t = threadIdx.x;
  int eh = t & 63, ls = t >> 6, l0 = lc * 256;
  float m = -1e30f, s = 0.f;
  for (int l = l0 + ls; l < l0 + 256; l += 4) {
    float x = sc[((size_t)(b*CL + l))*CEH + eh];
    float nm = fmaxf(m, x);
    s = s * __expf(m - nm) + __expf(x - nm);
    m = nm;
  }
  __shared__ float sm[4][64], ss[4][64];
  sm[ls][eh] = m; ss[ls][eh] = s;
  __syncthreads();
  if (ls == 0) {
    float M = sm[0][eh];
    for (int i = 1; i < 4; i++) M = fmaxf(M, sm[i][eh]);
    float S = 0.f;
    for (int i = 0; i < 4; i++) S += ss[i][eh] * __expf(sm[i][eh] - M);
    lmax[(size_t)(b*8 + lc)*CEH + eh] = M;
    lsum[(size_t)(b*8 + lc)*CEH + eh] = S;
  }
}

__global__ __launch_bounds__(64) void k5b_row(
    const float* __restrict__ lmax, const float* __restrict__ lsum,
    float* __restrict__ rmax, float* __restrict__ rinv) {
  int b = blockIdx.x, eh = threadIdx.x;
  float M = -1e30f;
  for (int c = 0; c < 8; c++) M = fmaxf(M, lmax[(b*8 + c)*CEH + eh]);
  float S = 0.f;
  for (int c = 0; c < 8; c++) S += lsum[(b*8 + c)*CEH + eh] * __expf(lmax[(b*8 + c)*CEH + eh] - M);
  rmax[b*CEH + eh] = M;
  rinv[b*CEH + eh] = 1.f / S;
}

__global__ __launch_bounds__(256) void k5c_norm_ent(
    float* __restrict__ sc, const float* __restrict__ rmax,
    const float* __restrict__ rinv, float* __restrict__ entp) {
  int b = blockIdx.y, lc = blockIdx.x, t = threadIdx.x;
  int eh = t & 63, ls = t >> 6, l0 = lc * 256;
  float M = rmax[b*CEH + eh], inv = rinv[b*CEH + eh];
  float ent = 0.f;
  for (int l = l0 + ls; l < l0 + 256; l += 4) {
    size_t ix = ((size_t)(b*CL + l))*CEH + eh;
    float p = __expf(sc[ix] - M) * inv;
    sc[ix] = p;
    float ps = p;
    ps += __shfl_xor(ps, 1);
    ps += __shfl_xor(ps, 2);
    ps += __shfl_xor(ps, 4);
    if ((eh & 7) == 0) {
      float pb = fmaxf(ps * 0.125f, 1e-12f);
      ent -= pb * logf(pb);
    }
  }
  __shared__ float es[4][8];
  if ((eh & 7) == 0) es[ls][eh >> 3] = ent;
  __syncthreads();
  if (t < 8) {
    entp[(b*CE + t)*8 + lc] = es[0][t] + es[1][t] + es[2][t] + es[3][t];
  }
}

// reff[b][eh][d] = sum_l P[b][l][eh] * R[b][l][d], split over 4 L-chunks x 8 d-tiles
__global__ __launch_bounds__(256) void k6_reff_split(
    const float* __restrict__ sc, const float* __restrict__ ret,
    float* __restrict__ reff, float* __restrict__ part) {
  int b = blockIdx.y;
  int dt = blockIdx.x & 7, lc = blockIdx.x >> 3;   // dtiles=8, lchunks=4
  int d0 = dt * 64, l0 = lc * 512;
  __shared__ __align__(16) float Ps[32][68];
  __shared__ __align__(16) float Rs[32][68];
  int t = threadIdx.x;
  int di = t & 15, ej = t >> 4;
  int f4 = t & 15, lrow = t >> 4;
  float acc[4][4] = {};
  const float* scb  = sc  + (size_t)(b*CL + l0)*CEH;
  const float* retb = ret + (size_t)(b*CL + l0)*CD + d0;
  for (int ls = 0; ls < 512; ls += 32) {
    #pragma unroll
    for (int p = 0; p < 2; p++) {
      float4 v = *reinterpret_cast<const float4*>(&scb[(size_t)(ls + p*16 + lrow)*CEH + f4*4]);
      *reinterpret_cast<float4*>(&Ps[p*16 + lrow][f4*4]) = v;
    }
    #pragma unroll
    for (int p = 0; p < 2; p++) {
      float4 v = *reinterpret_cast<const float4*>(&retb[(size_t)(ls + p*16 + lrow)*CD + f4*4]);
      *reinterpret_cast<float4*>(&Rs[p*16 + lrow][f4*4]) = v;
    }
    __syncthreads();
    #pragma unroll
    for (int l = 0; l < 32; l++) {
      float4 pv = *reinterpret_cast<const float4*>(&Ps[l][ej*4]);
      float4 rv = *reinterpret_cast<const float4*>(&Rs[l][di*4]);
      float pa[4] = {pv.x, pv.y, pv.z, pv.w};
      float ra[4] = {rv.x, rv.y, rv.z, rv.w};
      #pragma unroll
      for (int i = 0; i < 4; i++)
        #pragma unroll
        for (int j = 0; j < 4; j++)
          acc[i][j] += pa[i]*ra[j];
    }
    __syncthreads();
  }
  float* dst = (lc == 0) ? reff : (part + (size_t)(lc-1)*(CB*CEH*CD));
  #pragma unroll
  for (int i = 0; i < 4; i++) {
    int eh = ej*4 + i;
    float4 o = {acc[i][0], acc[i][1], acc[i][2], acc[i][3]};
    *reinterpret_cast<float4*>(&dst[((size_t)(b*CEH + eh))*CD + d0 + di*4]) = o;
  }
}

__global__ __launch_bounds__(256) void k6_comb(
    float* __restrict__ reff, const float* __restrict__ part) {
  int i = blockIdx.x*256 + threadIdx.x;   // over CB*CEH*CD/4 = 131072 float4
  float4 a = reinterpret_cast<float4*>(reff)[i];
  #pragma unroll
  for (int c = 0; c < 3; c++) {
    float4 p = reinterpret_cast<const float4*>(part + (size_t)c*(CB*CEH*CD))[i];
    a.x += p.x; a.y += p.y; a.z += p.z; a.w += p.w;
  }
  reinterpret_cast<float4*>(reff)[i] = a;
}

__global__ __launch_bounds__(256) void k7_lno(
    const float* __restrict__ x, const float* __restrict__ g,
    const float* __restrict__ bb, float* __restrict__ xo) {
  int be = blockIdx.x, e = be & 7, t = threadIdx.x;
  __shared__ float red[256];
  const float* xr = x + (size_t)be*CD;
  float v0 = xr[t], v1 = xr[256 + t];
  red[t] = v0 + v1; __syncthreads();
  for (int s = 128; s > 0; s >>= 1) { if (t < s) red[t] += red[t+s]; __syncthreads(); }
  float mu = red[0] * (1.0f/CD); __syncthreads();
  float c0 = v0 - mu, c1 = v1 - mu;
  red[t] = c0*c0 + c1*c1; __syncthreads();
  for (int s = 128; s > 0; s >>= 1) { if (t < s) red[t] += red[t+s]; __syncthreads(); }
  float rstd = rsqrtf(red[0] * (1.0f/CD) + 1e-5f);
  xo[be*CD + t]       = c0*rstd*g[e*CD + t]       + bb[e*CD + t];
  xo[be*CD + 256 + t] = c1*rstd*g[e*CD + 256 + t] + bb[e*CD + 256 + t];
}

__global__ __launch_bounds__(512) void k10_final(
    const float* __restrict__ gates, const float* __restrict__ entp,
    const float* __restrict__ yout, float* __restrict__ fused,
    float* __restrict__ gtout) {
  int b = blockIdx.x, t = threadIdx.x;
  __shared__ float gt_s[CE];
  if (t < CE) {
    float Hs = 0.f;
    for (int c = 0; c < 8; c++) Hs += entp[(b*CE + t)*8 + c];
    gt_s[t] = gates[b*CE + t] * __expf(-0.5f * Hs);
  }
  __syncthreads();
  if (t == 0) {
    float s = 0.f;
    for (int e = 0; e < CE; e++) s += gt_s[e];
    s += 1e-9f;
    for (int e = 0; e < CE; e++) { gt_s[e] /= s; gtout[b*CE + e] = gt_s[e]; }
  }
  __syncthreads();
  float acc = 0.f;
  #pragma unroll
  for (int e = 0; e < CE; e++) acc += gt_s[e] * yout[(b*CE + e)*CD + t];
  fused[b*CD + t] = acc;  // ALPHA = 1.0 -> fused == mixture
}

extern "C" void kernel_launch(void* const* d_in, const int* in_sizes, int n_in,
                              void* d_out, int out_size, void* d_ws, size_t ws_size,
                              hipStream_t stream) {
  const float* q    = (const float*)d_in[0];
  const float* ret  = (const float*)d_in[1];
  const float* wg   = (const float*)d_in[2];
  const float* lnqg = (const float*)d_in[3];
  const float* lnqb = (const float*)d_in[4];
  const float* Wq   = (const float*)d_in[5];
  const float* bq   = (const float*)d_in[6];
  const float* Wk   = (const float*)d_in[7];
  const float* bk   = (const float*)d_in[8];
  const float* Wv   = (const float*)d_in[9];
  const float* bv   = (const float*)d_in[10];
  const float* Wo   = (const float*)d_in[11];
  const float* bo   = (const float*)d_in[12];
  const float* lnog = (const float*)d_in[13];
  const float* lnob = (const float*)d_in[14];
  const float* W1   = (const float*)d_in[15];
  const float* b1   = (const float*)d_in[16];
  const float* W2   = (const float*)d_in[17];
  const float* b2   = (const float*)d_in[18];

  float* ws = (float*)d_ws;
  float* fused = (float*)d_out;
  float* yout  = fused + CB*CD;
  float* gtout = yout + CB*CE*CD;

  float* gates = ws + WS_GATES;
  float* xn    = ws + WS_XN;
  float* qn    = ws + WS_QN;
  float* qh    = ws + WS_QH;
  float* sbias = ws + WS_SBIAS;
  float* wkeff = ws + WS_WK;
  float* sc    = ws + WS_SC;
  float* part  = ws + WS_PART;
  float* lmax  = ws + WS_LMAX;
  float* lsum  = ws + WS_LSUM;
  float* rmax  = ws + WS_RMAX;
  float* rinv  = ws + WS_RINV;
  float* entp  = ws + WS_ENT;
  float* reff  = ws + WS_REFF;
  float* attn  = ws + WS_ATTN;
  float* xb    = ws + WS_X;
  float* xo    = ws + WS_XO;
  float* hbuf  = ws + WS_HB;
  float* rpart = ws + WS_RP;

  k1_gates_xn<<<CB, 256, 0, stream>>>(q, wg, xn, gates);
  k1b_qn<<<256, 256, 0, stream>>>(xn, lnqg, lnqb, qn);
  // qh = qn @ Wq + bq : K=512 (8 chunks of 64), N=512 (8 tiles)
  gstream<64><<<dim3(64, CE), 256, 0, stream>>>(qn, CE*CD, CD, Wq, (size_t)CD*CD, CD,
                                                part, 8, 65536, CE*CD, CD);
  comb8_bias<<<256, 256, 0, stream>>>(part, bq, qh);
  k3_sbias<<<CB*CE, 64, 0, stream>>>(qh, bk, sbias);
  k4_wkeff<<<dim3(64, CE), 256, 0, stream>>>(Wk, qh, wkeff);
  k5_scores<<<dim3(32, CB), 256, 0, stream>>>(ret, wkeff, sbias, sc);
  k5s_stats<<<dim3(8, CB), 256, 0, stream>>>(sc, lmax, lsum);
  k5b_row<<<CB, 64, 0, stream>>>(lmax, lsum, rmax, rinv);
  k5c_norm_ent<<<dim3(8, CB), 256, 0, stream>>>(sc, rmax, rinv, entp);
  k6_reff_split<<<dim3(32, CB), 256, 0, stream>>>(sc, ret, reff, rpart);
  k6_comb<<<512, 256, 0, stream>>>(reff, rpart);
  // attn = reff @ Wv + bv : per (e,h), K=512 (8 chunks)
  gstream_v<<<dim3(8, CEH), 256, 0, stream>>>(reff, Wv, part);
  comb8_bias<<<256, 256, 0, stream>>>(part, bv, attn);
  // x = q + attn @ Wo + bo
  gstream<64><<<dim3(64, CE), 256, 0, stream>>>(attn, CE*CD, CD, Wo, (size_t)CD*CD, CD,
                                                part, 8, 65536, CE*CD, CD);
  comb8_o<<<256, 256, 0, stream>>>(part, bo, q, xb);
  k7_lno<<<CB*CE, 256, 0, stream>>>(xb, lnog, lnob, xo);
  // h = gelu(xo @ W1 + b1) : K=512 (4 chunks of 128), N=2048 (32 tiles)
  gstream<128><<<dim3(128, CE), 256, 0, stream>>>(xo, CE*CD, CD, W1, (size_t)CD*CF, CF,
                                                  part, 32, 262144, CE*CF, CF);
  comb4_gelu<<<1024, 256, 0, stream>>>(part, b1, hbuf);
  // y = h @ W2 + b2 + x : K=2048 (8 chunks of 256), N=512 (8 tiles)
  gstream<256><<<dim3(64, CE), 256, 0, stream>>>(hbuf, CE*CF, CF, W2, (size_t)CF*CD, CD,
                                                 part, 8, 65536, CE*CD, CD);
  comb8_ffn2<<<256, 256, 0, stream>>>(part, b2, xb, yout);
  k10_final<<<CB, 512, 0, stream>>>(gates, entp, yout, fused, gtout);
}

// Round 4
// 170.083 us; speedup vs baseline: 3.4245x; 1.1612x over previous
//
#include <hip/hip_runtime.h>
#include <math.h>

#define CB 16
#define CL 2048
#define CD 512
#define CE 8
#define CH 8
#define CEH 64
#define CF 2048

typedef __bf16 bf16x8 __attribute__((ext_vector_type(8)));
typedef float f32x4 __attribute__((ext_vector_type(4)));

// ws layout (float offsets)
#define WS_GATES 0
#define WS_XN    (WS_GATES + CB*CE)
#define WS_QN    (WS_XN + CB*CD)
#define WS_QH    (WS_QN + CB*CE*CD)
#define WS_SBIAS (WS_QH + CB*CE*CD)
#define WS_WK    (WS_SBIAS + CB*CE*CH)          /* holds bf16 wkh [b][eh][d] */
#define WS_SC    (WS_WK + CB*CEH*CD)            /* fp32 sc [b][eh][l] */
#define WS_PART  WS_SC   /* gstream partial buffers alias sc: liveness disjoint */
#define WS_RMAX  (WS_SC + CB*CL*CEH)
#define WS_RINV  (WS_RMAX + CB*CEH)
#define WS_ENT   (WS_RINV + CB*CEH)
#define WS_REFF  (WS_ENT + CB*CE)
#define WS_ATTN  (WS_REFF + CB*CEH*CD)
#define WS_X     (WS_ATTN + CB*CE*CD)
#define WS_XO    (WS_X + CB*CE*CD)
#define WS_HB    (WS_XO + CB*CE*CD)
#define WS_RP    (WS_HB + CB*CE*CF)   /* 3 * CB*CEH*CD fp32 partials for k6; lmax/lsum alias its head */

__global__ __launch_bounds__(256) void k1_gates_xn(
    const float* __restrict__ q, const float* __restrict__ wg,
    float* __restrict__ xn, float* __restrict__ gates) {
  int b = blockIdx.x, t = threadIdx.x;
  __shared__ float red[256];
  __shared__ float logits[CE];
  float v0 = q[b*CD + t], v1 = q[b*CD + 256 + t];
  red[t] = v0 + v1; __syncthreads();
  for (int s = 128; s > 0; s >>= 1) { if (t < s) red[t] += red[t+s]; __syncthreads(); }
  float mu = red[0] * (1.0f/CD); __syncthreads();
  float c0 = v0 - mu, c1 = v1 - mu;
  red[t] = c0*c0 + c1*c1; __syncthreads();
  for (int s = 128; s > 0; s >>= 1) { if (t < s) red[t] += red[t+s]; __syncthreads(); }
  float rstd = rsqrtf(red[0] * (1.0f/CD) + 1e-5f); __syncthreads();
  xn[b*CD + t] = c0 * rstd;
  xn[b*CD + 256 + t] = c1 * rstd;
  float ge[CE];
  #pragma unroll
  for (int e = 0; e < CE; e++) ge[e] = v0 * wg[t*CE + e] + v1 * wg[(256+t)*CE + e];
  for (int e = 0; e < CE; e++) {
    red[t] = ge[e]; __syncthreads();
    for (int s = 128; s > 0; s >>= 1) { if (t < s) red[t] += red[t+s]; __syncthreads(); }
    if (t == 0) logits[e] = red[0];
    __syncthreads();
  }
  if (t == 0) {
    float m = logits[0];
    for (int e = 1; e < CE; e++) m = fmaxf(m, logits[e]);
    float s = 0.f, ex[CE];
    for (int e = 0; e < CE; e++) { ex[e] = __expf(logits[e] - m); s += ex[e]; }
    for (int e = 0; e < CE; e++) gates[b*CE + e] = ex[e] / s;
  }
}

__global__ __launch_bounds__(256) void k1b_qn(
    const float* __restrict__ xn, const float* __restrict__ g,
    const float* __restrict__ bln, float* __restrict__ qn) {
  int i = blockIdx.x*256 + threadIdx.x;      // flat [b][e][d], 65536
  int b = i >> 12, e = (i >> 9) & 7, d = i & 511;
  qn[i] = xn[b*CD + d] * g[e*CD + d] + bln[e*CD + d];
}

// Streaming split-K GEMV16: out_partial[kc][b][e][n] = sum_k X[b,e,k]*W[e,k,n]
template<int KC>
__global__ __launch_bounds__(256) void gstream(
    const float* __restrict__ X, int xb_, int xe_,
    const float* __restrict__ W, size_t we_, int ldw,
    float* __restrict__ P, int ntiles, size_t pc_, int pb_, int pe_) {
  int e = blockIdx.y;
  int nt = blockIdx.x % ntiles, kc = blockIdx.x / ntiles;
  int n0 = nt * 64, k0 = kc * KC;
  __shared__ float xs[KC][16];
  __shared__ float red[16][64];
  int t = threadIdx.x;
  for (int idx = t; idx < KC * 16; idx += 256) {
    int k = idx >> 4, b = idx & 15;
    xs[k][b] = X[(size_t)b * xb_ + (size_t)e * xe_ + k0 + k];
  }
  __syncthreads();
  int n = t & 63, kq = t >> 6;
  float acc[16] = {};
  const float* Wp = W + (size_t)e * we_ + (size_t)k0 * ldw + n0 + n;
  #pragma unroll 4
  for (int k = kq * (KC/4); k < (kq+1) * (KC/4); k++) {
    float w = Wp[(size_t)k * ldw];
    const float4* xp = reinterpret_cast<const float4*>(xs[k]);
    float4 x0 = xp[0], x1 = xp[1], x2 = xp[2], x3 = xp[3];
    acc[0]  += x0.x*w; acc[1]  += x0.y*w; acc[2]  += x0.z*w; acc[3]  += x0.w*w;
    acc[4]  += x1.x*w; acc[5]  += x1.y*w; acc[6]  += x1.z*w; acc[7]  += x1.w*w;
    acc[8]  += x2.x*w; acc[9]  += x2.y*w; acc[10] += x2.z*w; acc[11] += x2.w*w;
    acc[12] += x3.x*w; acc[13] += x3.y*w; acc[14] += x3.z*w; acc[15] += x3.w*w;
  }
  if (kq == 0) {
    #pragma unroll
    for (int b = 0; b < 16; b++) red[b][n] = acc[b];
  }
  __syncthreads();
  #pragma unroll
  for (int qq = 1; qq < 4; qq++) {
    if (kq == qq) {
      #pragma unroll
      for (int b = 0; b < 16; b++) red[b][n] += acc[b];
    }
    __syncthreads();
  }
  #pragma unroll
  for (int i = 0; i < 4; i++) {
    int b = kq*4 + i;
    P[(size_t)kc*pc_ + (size_t)b*pb_ + (size_t)e*pe_ + n0 + n] = red[b][n];
  }
}

// Wv variant: per (eh) block column h*64..h*64+63, split over d (K=512, 8 chunks)
__global__ __launch_bounds__(256) void gstream_v(
    const float* __restrict__ reff, const float* __restrict__ Wv,
    float* __restrict__ P) {
  int eh = blockIdx.y, kc = blockIdx.x;
  int e = eh >> 3, h = eh & 7;
  int k0 = kc * 64;
  __shared__ float xs[64][16];
  __shared__ float red[16][64];
  int t = threadIdx.x;
  for (int idx = t; idx < 64 * 16; idx += 256) {
    int k = idx >> 4, b = idx & 15;
    xs[k][b] = reff[((size_t)(b*CEH + eh))*CD + k0 + k];
  }
  __syncthreads();
  int n = t & 63, kq = t >> 6;
  float acc[16] = {};
  const float* Wp = Wv + (size_t)e*CD*CD + (size_t)k0*CD + h*64 + n;
  #pragma unroll 4
  for (int k = kq*16; k < kq*16 + 16; k++) {
    float w = Wp[(size_t)k * CD];
    const float4* xp = reinterpret_cast<const float4*>(xs[k]);
    float4 x0 = xp[0], x1 = xp[1], x2 = xp[2], x3 = xp[3];
    acc[0]  += x0.x*w; acc[1]  += x0.y*w; acc[2]  += x0.z*w; acc[3]  += x0.w*w;
    acc[4]  += x1.x*w; acc[5]  += x1.y*w; acc[6]  += x1.z*w; acc[7]  += x1.w*w;
    acc[8]  += x2.x*w; acc[9]  += x2.y*w; acc[10] += x2.z*w; acc[11] += x2.w*w;
    acc[12] += x3.x*w; acc[13] += x3.y*w; acc[14] += x3.z*w; acc[15] += x3.w*w;
  }
  if (kq == 0) { 
    #pragma unroll
    for (int b = 0; b < 16; b++) red[b][n] = acc[b]; }
  __syncthreads();
  #pragma unroll
  for (int qq = 1; qq < 4; qq++) {
    if (kq == qq) {
      #pragma unroll
      for (int b = 0; b < 16; b++) red[b][n] += acc[b];
    }
    __syncthreads();
  }
  #pragma unroll
  for (int i = 0; i < 4; i++) {
    int b = kq*4 + i;
    P[(size_t)kc*65536 + (size_t)b*4096 + (size_t)eh*64 + n] = red[b][n];
  }
}

__global__ __launch_bounds__(256) void comb8_bias(
    const float* __restrict__ P, const float* __restrict__ bias,
    float* __restrict__ out) {
  int i = blockIdx.x*256 + threadIdx.x;
  float s = bias[i & 4095];
  #pragma unroll
  for (int c = 0; c < 8; c++) s += P[(size_t)c*65536 + i];
  out[i] = s;
}

__global__ __launch_bounds__(256) void comb8_o(
    const float* __restrict__ P, const float* __restrict__ bias,
    const float* __restrict__ q, float* __restrict__ x) {
  int i = blockIdx.x*256 + threadIdx.x;
  float s = bias[i & 4095] + q[(i >> 12)*CD + (i & 511)];
  #pragma unroll
  for (int c = 0; c < 8; c++) s += P[(size_t)c*65536 + i];
  x[i] = s;
}

__global__ __launch_bounds__(256) void comb4_gelu(
    const float* __restrict__ P, const float* __restrict__ bias,
    float* __restrict__ out) {
  int i = blockIdx.x*256 + threadIdx.x;   // flat [b][e][f], 262144
  float s = bias[i & 16383];
  #pragma unroll
  for (int c = 0; c < 4; c++) s += P[(size_t)c*262144 + i];
  out[i] = 0.5f*s*(1.f + erff(s*0.70710678118f));
}

__global__ __launch_bounds__(256) void comb8_ffn2(
    const float* __restrict__ P, const float* __restrict__ bias,
    const float* __restrict__ x, float* __restrict__ yout) {
  int i = blockIdx.x*256 + threadIdx.x;
  float s = bias[i & 4095] + x[i];
  #pragma unroll
  for (int c = 0; c < 8; c++) s += P[(size_t)c*65536 + i];
  yout[i] = s;
}

__global__ __launch_bounds__(64) void k3_sbias(
    const float* __restrict__ qh, const float* __restrict__ bk,
    float* __restrict__ sbias) {
  int be = blockIdx.x, b = be >> 3, e = be & 7, t = threadIdx.x;
  for (int h = 0; h < CH; h++) {
    float v = qh[(b*CE + e)*CD + h*64 + t] * bk[e*CD + h*64 + t];
    for (int off = 32; off > 0; off >>= 1) v += __shfl_down(v, off);
    if (t == 0) sbias[(b*CE + e)*CH + h] = v;
  }
}

__global__ __launch_bounds__(256) void k4_wkeff(
    const float* __restrict__ Wk, const float* __restrict__ qh,
    __bf16* __restrict__ wkh) {
  int e = blockIdx.y;
  int h = blockIdx.x >> 3, dt = blockIdx.x & 7;
  int d0 = dt * 64;
  __shared__ float wks[64][65];   // [c][d]
  __shared__ float qs[64][16];    // [c][b]
  __shared__ float red[16][64];
  int t = threadIdx.x;
  for (int idx = t; idx < 64*64; idx += 256) {
    int c = idx & 63, d = idx >> 6;
    wks[c][d] = Wk[(size_t)e*CD*CD + (size_t)(d0+d)*CD + h*64 + c];
  }
  for (int idx = t; idx < 64*16; idx += 256) {
    int c = idx >> 4, b = idx & 15;
    qs[c][b] = qh[(b*CE + e)*CD + h*64 + c];
  }
  __syncthreads();
  int d = t & 63, cq = t >> 6;
  float acc[16] = {};
  #pragma unroll 4
  for (int c = cq*16; c < cq*16 + 16; c++) {
    float w = wks[c][d];
    const float4* xp = reinterpret_cast<const float4*>(qs[c]);
    float4 x0 = xp[0], x1 = xp[1], x2 = xp[2], x3 = xp[3];
    acc[0]  += x0.x*w; acc[1]  += x0.y*w; acc[2]  += x0.z*w; acc[3]  += x0.w*w;
    acc[4]  += x1.x*w; acc[5]  += x1.y*w; acc[6]  += x1.z*w; acc[7]  += x1.w*w;
    acc[8]  += x2.x*w; acc[9]  += x2.y*w; acc[10] += x2.z*w; acc[11] += x2.w*w;
    acc[12] += x3.x*w; acc[13] += x3.y*w; acc[14] += x3.z*w; acc[15] += x3.w*w;
  }
  if (cq == 0) { 
    #pragma unroll
    for (int b = 0; b < 16; b++) red[b][d] = acc[b]; }
  __syncthreads();
  #pragma unroll
  for (int qq = 1; qq < 4; qq++) {
    if (cq == qq) {
      #pragma unroll
      for (int b = 0; b < 16; b++) red[b][d] += acc[b];
    }
    __syncthreads();
  }
  int eh = e*8 + h;
  #pragma unroll
  for (int i = 0; i < 4; i++) {
    int b = cq*4 + i;
    wkh[((size_t)(b*CEH + eh))*CD + d0 + d] = (__bf16)red[b][d];
  }
}

// sc[b][eh][l] = (ret[b][l][:]·wk_eff[b][eh][:] + qh·bk)/8 via bf16 MFMA.
// Also emits per-16l-strip (max, expsum) for the row softmax.
__global__ __launch_bounds__(256) void k5_mfma(
    const float* __restrict__ ret, const __bf16* __restrict__ wkh,
    const float* __restrict__ sbias, float* __restrict__ sc,
    float* __restrict__ lmax, float* __restrict__ lsum) {
  int b = blockIdx.y, lt = blockIdx.x, t = threadIdx.x;
  int w = t >> 6, lane = t & 63;
  int lnlo = lane & 15, lnhi = lane >> 4;
  int l0 = lt*64 + w*16;
  f32x4 acc[4];
  #pragma unroll
  for (int et = 0; et < 4; et++) acc[et] = (f32x4){0.f,0.f,0.f,0.f};
  const float* retb = ret + ((size_t)(b*CL) + l0 + lnlo)*CD + lnhi*8;
  const __bf16* wb = wkh + (size_t)b*CEH*CD + (size_t)lnlo*CD + lnhi*8;
  for (int ks = 0; ks < 16; ks++) {
    int d = ks*32;
    float4 f0 = *reinterpret_cast<const float4*>(retb + d);
    float4 f1 = *reinterpret_cast<const float4*>(retb + d + 4);
    bf16x8 bfrag;
    bfrag[0]=(__bf16)f0.x; bfrag[1]=(__bf16)f0.y; bfrag[2]=(__bf16)f0.z; bfrag[3]=(__bf16)f0.w;
    bfrag[4]=(__bf16)f1.x; bfrag[5]=(__bf16)f1.y; bfrag[6]=(__bf16)f1.z; bfrag[7]=(__bf16)f1.w;
    #pragma unroll
    for (int et = 0; et < 4; et++) {
      bf16x8 afrag = *reinterpret_cast<const bf16x8*>(wb + (size_t)et*16*CD + d);
      acc[et] = __builtin_amdgcn_mfma_f32_16x16x32_bf16(afrag, bfrag, acc[et], 0, 0, 0);
    }
  }
  int strip = lt*4 + w;
  int l = l0 + lnlo;
  #pragma unroll
  for (int et = 0; et < 4; et++) {
    #pragma unroll
    for (int i = 0; i < 4; i++) {
      int eh = et*16 + lnhi*4 + i;
      float v = acc[et][i]*0.125f + sbias[b*CEH + eh]*0.125f;
      sc[((size_t)(b*CEH + eh))*CL + l] = v;
      float m = v;
      m = fmaxf(m, __shfl_xor(m, 1));
      m = fmaxf(m, __shfl_xor(m, 2));
      m = fmaxf(m, __shfl_xor(m, 4));
      m = fmaxf(m, __shfl_xor(m, 8));
      float s = __expf(v - m);
      s += __shfl_xor(s, 1);
      s += __shfl_xor(s, 2);
      s += __shfl_xor(s, 4);
      s += __shfl_xor(s, 8);
      if (lnlo == et*4 + i) {
        lmax[((size_t)(b*CEH + eh))*128 + strip] = m;
        lsum[((size_t)(b*CEH + eh))*128 + strip] = s;
      }
    }
  }
}

__global__ __launch_bounds__(256) void k5b2(
    const float* __restrict__ lmax, const float* __restrict__ lsum,
    float* __restrict__ rmax, float* __restrict__ rinv) {
  int b = blockIdx.x, t = threadIdx.x, eh = t & 63, q = t >> 6;
  const float* lm = lmax + ((size_t)(b*CEH + eh))*128 + q*32;
  const float* ls = lsum + ((size_t)(b*CEH + eh))*128 + q*32;
  float M = -1e30f, S = 0.f;
  for (int i = 0; i < 32; i++) {
    float m2 = lm[i], s2 = ls[i];
    float Mn = fmaxf(M, m2);
    S = S*__expf(M - Mn) + s2*__expf(m2 - Mn);
    M = Mn;
  }
  __shared__ float sm[4][64], ss[4][64];
  sm[q][eh] = M; ss[q][eh] = S;
  __syncthreads();
  if (q == 0) {
    #pragma unroll
    for (int i = 1; i < 4; i++) {
      float m2 = sm[i][eh], s2 = ss[i][eh];
      float Mn = fmaxf(M, m2);
      S = S*__expf(M - Mn) + s2*__expf(m2 - Mn);
      M = Mn;
    }
    rmax[b*CEH + eh] = M;
    rinv[b*CEH + eh] = 1.f / S;
  }
}

// normalize sc in place to probs; entropy of head-averaged probs per (b,e)
__global__ __launch_bounds__(256) void k5n(
    float* __restrict__ sc, const float* __restrict__ rmax,
    const float* __restrict__ rinv, float* __restrict__ entp) {
  int e = blockIdx.x, b = blockIdx.y, t = threadIdx.x;
  float M[8], inv[8];
  #pragma unroll
  for (int h = 0; h < 8; h++) {
    M[h] = rmax[b*CEH + e*8 + h];
    inv[h] = rinv[b*CEH + e*8 + h];
  }
  float ent = 0.f;
  for (int j = 0; j < 8; j++) {
    int l = j*256 + t;
    float pb = 0.f;
    #pragma unroll
    for (int h = 0; h < 8; h++) {
      size_t ix = ((size_t)(b*CEH + e*8 + h))*CL + l;
      float p = __expf(sc[ix] - M[h]) * inv[h];
      sc[ix] = p;
      pb += p;
    }
    pb = fmaxf(pb*0.125f, 1e-12f);
    ent -= pb * __logf(pb);
  }
  __shared__ float red[256];
  red[t] = ent; __syncthreads();
  for (int s = 128; s > 0; s >>= 1) { if (t < s) red[t] += red[t+s]; __syncthreads(); }
  if (t == 0) entp[b*CE + e] = red[0];
}

// reff[b][eh][d] = sum_l P[b][eh][l] * ret[b][l][d] via bf16 MFMA.
// 8 d-tiles x 4 L-chunks; lc>0 writes fp32 partials.
__global__ __launch_bounds__(256) void k6_mfma(
    const float* __restrict__ sc, const float* __restrict__ ret,
    float* __restrict__ reff, float* __restrict__ part) {
  int b = blockIdx.y;
  int dt = blockIdx.x & 7, lc = blockIdx.x >> 3;
  int d0 = dt*64, l0 = lc*512;
  int t = threadIdx.x, w = t >> 6, lane = t & 63;
  int lnlo = lane & 15, lnhi = lane >> 4;
  __shared__ __bf16 Bs[64][40];   // [d][l] K-major tile, padded rows (80B, 16B-aligned chunks)
  f32x4 acc[4];
  #pragma unroll
  for (int et = 0; et < 4; et++) acc[et] = (f32x4){0.f,0.f,0.f,0.f};
  const float* scb = sc + ((size_t)(b*CEH) + lnlo)*CL + l0 + lnhi*8;
  int srow = t & 31, scol = (t >> 5)*8;
  const float* retb = ret + ((size_t)(b*CL) + l0 + srow)*CD + d0 + scol;
  for (int kt = 0; kt < 16; kt++) {
    __syncthreads();
    float4 v0 = *reinterpret_cast<const float4*>(retb + (size_t)kt*32*CD);
    float4 v1 = *reinterpret_cast<const float4*>(retb + (size_t)kt*32*CD + 4);
    Bs[scol+0][srow] = (__bf16)v0.x; Bs[scol+1][srow] = (__bf16)v0.y;
    Bs[scol+2][srow] = (__bf16)v0.z; Bs[scol+3][srow] = (__bf16)v0.w;
    Bs[scol+4][srow] = (__bf16)v1.x; Bs[scol+5][srow] = (__bf16)v1.y;
    Bs[scol+6][srow] = (__bf16)v1.z; Bs[scol+7][srow] = (__bf16)v1.w;
    __syncthreads();
    bf16x8 bfrag = *reinterpret_cast<const bf16x8*>(&Bs[w*16 + lnlo][lnhi*8]);
    #pragma unroll
    for (int et = 0; et < 4; et++) {
      const float* ap = scb + (size_t)et*16*CL + kt*32;
      float4 p0 = *reinterpret_cast<const float4*>(ap);
      float4 p1 = *reinterpret_cast<const float4*>(ap + 4);
      bf16x8 afrag;
      afrag[0]=(__bf16)p0.x; afrag[1]=(__bf16)p0.y; afrag[2]=(__bf16)p0.z; afrag[3]=(__bf16)p0.w;
      afrag[4]=(__bf16)p1.x; afrag[5]=(__bf16)p1.y; afrag[6]=(__bf16)p1.z; afrag[7]=(__bf16)p1.w;
      acc[et] = __builtin_amdgcn_mfma_f32_16x16x32_bf16(afrag, bfrag, acc[et], 0, 0, 0);
    }
  }
  float* dst = (lc == 0) ? reff : (part + (size_t)(lc-1)*(CB*CEH*CD));
  int d = d0 + w*16 + lnlo;
  #pragma unroll
  for (int et = 0; et < 4; et++) {
    #pragma unroll
    for (int i = 0; i < 4; i++) {
      int eh = et*16 + lnhi*4 + i;
      dst[((size_t)(b*CEH + eh))*CD + d] = acc[et][i];
    }
  }
}

__global__ __launch_bounds__(256) void k6_comb(
    float* __restrict__ reff, const float* __restrict__ part) {
  int i = blockIdx.x*256 + threadIdx.x;   // over CB*CEH*CD/4 = 131072 float4
  float4 a = reinterpret_cast<float4*>(reff)[i];
  #pragma unroll
  for (int c = 0; c < 3; c++) {
    float4 p = reinterpret_cast<const float4*>(part + (size_t)c*(CB*CEH*CD))[i];
    a.x += p.x; a.y += p.y; a.z += p.z; a.w += p.w;
  }
  reinterpret_cast<float4*>(reff)[i] = a;
}

__global__ __launch_bounds__(256) void k7_lno(
    const float* __restrict__ x, const float* __restrict__ g,
    const float* __restrict__ bb, float* __restrict__ xo) {
  int be = blockIdx.x, e = be & 7, t = threadIdx.x;
  __shared__ float red[256];
  const float* xr = x + (size_t)be*CD;
  float v0 = xr[t], v1 = xr[256 + t];
  red[t] = v0 + v1; __syncthreads();
  for (int s = 128; s > 0; s >>= 1) { if (t < s) red[t] += red[t+s]; __syncthreads(); }
  float mu = red[0] * (1.0f/CD); __syncthreads();
  float c0 = v0 - mu, c1 = v1 - mu;
  red[t] = c0*c0 + c1*c1; __syncthreads();
  for (int s = 128; s > 0; s >>= 1) { if (t < s) red[t] += red[t+s]; __syncthreads(); }
  float rstd = rsqrtf(red[0] * (1.0f/CD) + 1e-5f);
  xo[be*CD + t]       = c0*rstd*g[e*CD + t]       + bb[e*CD + t];
  xo[be*CD + 256 + t] = c1*rstd*g[e*CD + 256 + t] + bb[e*CD + 256 + t];
}

__global__ __launch_bounds__(512) void k10_final(
    const float* __restrict__ gates, const float* __restrict__ entp,
    const float* __restrict__ yout, float* __restrict__ fused,
    float* __restrict__ gtout) {
  int b = blockIdx.x, t = threadIdx.x;
  __shared__ float gt_s[CE];
  if (t < CE) {
    gt_s[t] = gates[b*CE + t] * __expf(-0.5f * entp[b*CE + t]);
  }
  __syncthreads();
  if (t == 0) {
    float s = 0.f;
    for (int e = 0; e < CE; e++) s += gt_s[e];
    s += 1e-9f;
    for (int e = 0; e < CE; e++) { gt_s[e] /= s; gtout[b*CE + e] = gt_s[e]; }
  }
  __syncthreads();
  float acc = 0.f;
  #pragma unroll
  for (int e = 0; e < CE; e++) acc += gt_s[e] * yout[(b*CE + e)*CD + t];
  fused[b*CD + t] = acc;  // ALPHA = 1.0 -> fused == mixture
}

extern "C" void kernel_launch(void* const* d_in, const int* in_sizes, int n_in,
                              void* d_out, int out_size, void* d_ws, size_t ws_size,
                              hipStream_t stream) {
  const float* q    = (const float*)d_in[0];
  const float* ret  = (const float*)d_in[1];
  const float* wg   = (const float*)d_in[2];
  const float* lnqg = (const float*)d_in[3];
  const float* lnqb = (const float*)d_in[4];
  const float* Wq   = (const float*)d_in[5];
  const float* bq   = (const float*)d_in[6];
  const float* Wk   = (const float*)d_in[7];
  const float* bk   = (const float*)d_in[8];
  const float* Wv   = (const float*)d_in[9];
  const float* bv   = (const float*)d_in[10];
  const float* Wo   = (const float*)d_in[11];
  const float* bo   = (const float*)d_in[12];
  const float* lnog = (const float*)d_in[13];
  const float* lnob = (const float*)d_in[14];
  const float* W1   = (const float*)d_in[15];
  const float* b1   = (const float*)d_in[16];
  const float* W2   = (const float*)d_in[17];
  const float* b2   = (const float*)d_in[18];

  float* ws = (float*)d_ws;
  float* fused = (float*)d_out;
  float* yout  = fused + CB*CD;
  float* gtout = yout + CB*CE*CD;

  float* gates = ws + WS_GATES;
  float* xn    = ws + WS_XN;
  float* qn    = ws + WS_QN;
  float* qh    = ws + WS_QH;
  float* sbias = ws + WS_SBIAS;
  __bf16* wkh  = (__bf16*)(ws + WS_WK);
  float* sc    = ws + WS_SC;
  float* part  = ws + WS_PART;
  float* rmax  = ws + WS_RMAX;
  float* rinv  = ws + WS_RINV;
  float* entp  = ws + WS_ENT;
  float* reff  = ws + WS_REFF;
  float* attn  = ws + WS_ATTN;
  float* xb    = ws + WS_X;
  float* xo    = ws + WS_XO;
  float* hbuf  = ws + WS_HB;
  float* rpart = ws + WS_RP;
  float* lmax  = rpart;                      // dead before k6_mfma writes rpart
  float* lsum  = rpart + CB*CEH*128;

  k1_gates_xn<<<CB, 256, 0, stream>>>(q, wg, xn, gates);
  k1b_qn<<<256, 256, 0, stream>>>(xn, lnqg, lnqb, qn);
  // qh = qn @ Wq + bq : K=512 (8 chunks of 64), N=512 (8 tiles)
  gstream<64><<<dim3(64, CE), 256, 0, stream>>>(qn, CE*CD, CD, Wq, (size_t)CD*CD, CD,
                                                part, 8, 65536, CE*CD, CD);
  comb8_bias<<<256, 256, 0, stream>>>(part, bq, qh);
  k3_sbias<<<CB*CE, 64, 0, stream>>>(qh, bk, sbias);
  k4_wkeff<<<dim3(64, CE), 256, 0, stream>>>(Wk, qh, wkh);
  k5_mfma<<<dim3(32, CB), 256, 0, stream>>>(ret, wkh, sbias, sc, lmax, lsum);
  k5b2<<<CB, 256, 0, stream>>>(lmax, lsum, rmax, rinv);
  k5n<<<dim3(CE, CB), 256, 0, stream>>>(sc, rmax, rinv, entp);
  k6_mfma<<<dim3(32, CB), 256, 0, stream>>>(sc, ret, reff, rpart);
  k6_comb<<<512, 256, 0, stream>>>(reff, rpart);
  // attn = reff @ Wv + bv : per (e,h), K=512 (8 chunks)
  gstream_v<<<dim3(8, CEH), 256, 0, stream>>>(reff, Wv, part);
  comb8_bias<<<256, 256, 0, stream>>>(part, bv, attn);
  // x = q + attn @ Wo + bo
  gstream<64><<<dim3(64, CE), 256, 0, stream>>>(attn, CE*CD, CD, Wo, (size_t)CD*CD, CD,
                                                part, 8, 65536, CE*CD, CD);
  comb8_o<<<256, 256, 0, stream>>>(part, bo, q, xb);
  k7_lno<<<CB*CE, 256, 0, stream>>>(xb, lnog, lnob, xo);
  // h = gelu(xo @ W1 + b1) : K=512 (4 chunks of 128), N=2048 (32 tiles)
  gstream<128><<<dim3(128, CE), 256, 0, stream>>>(xo, CE*CD, CD, W1, (size_t)CD*CF, CF,
                                                  part, 32, 262144, CE*CF, CF);
  comb4_gelu<<<1024, 256, 0, stream>>>(part, b1, hbuf);
  // y = h @ W2 + b2 + x : K=2048 (8 chunks of 256), N=512 (8 tiles)
  gstream<256><<<dim3(64, CE), 256, 0, stream>>>(hbuf, CE*CF, CF, W2, (size_t)CF*CD, CD,
                                                 part, 8, 65536, CE*CD, CD);
  comb8_ffn2<<<256, 256, 0, stream>>>(part, b2, xb, yout);
  k10_final<<<CB, 512, 0, stream>>>(gates, entp, yout, fused, gtout);
}

// Round 5
// 155.669 us; speedup vs baseline: 3.7416x; 1.0926x over previous
//
#include <hip/hip_runtime.h>
#include <math.h>

#define CB 16
#define CL 2048
#define CD 512
#define CE 8
#define CH 8
#define CEH 64
#define CF 2048

typedef __bf16 bf16x8 __attribute__((ext_vector_type(8)));
typedef float f32x4 __attribute__((ext_vector_type(4)));

// ws layout (float offsets)
#define WS_GATES 0
#define WS_XN    (WS_GATES + CB*CE)
#define WS_QN    (WS_XN + CB*CD)
#define WS_QH    (WS_QN + CB*CE*CD)
#define WS_SBIAS (WS_QH + CB*CE*CD)
#define WS_WK    (WS_SBIAS + CB*CE*CH)          /* holds bf16 wkh [b][eh][d] */
#define WS_SC    (WS_WK + CB*CEH*CD)            /* fp32 sc [b][eh][l] */
#define WS_PART  WS_SC   /* gstream partial buffers alias sc: liveness disjoint */
#define WS_RMAX  (WS_SC + CB*CL*CEH)
#define WS_RINV  (WS_RMAX + CB*CEH)
#define WS_ENT   (WS_RINV + CB*CEH)
#define WS_ATTN  (WS_ENT + CB*CE)
#define WS_X     (WS_ATTN + CB*CE*CD)
#define WS_XO    (WS_X + CB*CE*CD)
#define WS_HB    (WS_XO + CB*CE*CD)
#define WS_RP    (WS_HB + CB*CE*CF)             /* 8 * CB*CEH*CD fp32 partials for k6; lmax/lsum alias head */
#define WS_PB16  (WS_RP + 8*CB*CEH*CD)          /* bf16 probs [b][eh][l] */

__global__ __launch_bounds__(256) void k1_gates_xn(
    const float* __restrict__ q, const float* __restrict__ wg,
    float* __restrict__ xn, float* __restrict__ gates) {
  int b = blockIdx.x, t = threadIdx.x;
  __shared__ float red[256];
  __shared__ float logits[CE];
  float v0 = q[b*CD + t], v1 = q[b*CD + 256 + t];
  red[t] = v0 + v1; __syncthreads();
  for (int s = 128; s > 0; s >>= 1) { if (t < s) red[t] += red[t+s]; __syncthreads(); }
  float mu = red[0] * (1.0f/CD); __syncthreads();
  float c0 = v0 - mu, c1 = v1 - mu;
  red[t] = c0*c0 + c1*c1; __syncthreads();
  for (int s = 128; s > 0; s >>= 1) { if (t < s) red[t] += red[t+s]; __syncthreads(); }
  float rstd = rsqrtf(red[0] * (1.0f/CD) + 1e-5f); __syncthreads();
  xn[b*CD + t] = c0 * rstd;
  xn[b*CD + 256 + t] = c1 * rstd;
  float ge[CE];
  #pragma unroll
  for (int e = 0; e < CE; e++) ge[e] = v0 * wg[t*CE + e] + v1 * wg[(256+t)*CE + e];
  for (int e = 0; e < CE; e++) {
    red[t] = ge[e]; __syncthreads();
    for (int s = 128; s > 0; s >>= 1) { if (t < s) red[t] += red[t+s]; __syncthreads(); }
    if (t == 0) logits[e] = red[0];
    __syncthreads();
  }
  if (t == 0) {
    float m = logits[0];
    for (int e = 1; e < CE; e++) m = fmaxf(m, logits[e]);
    float s = 0.f, ex[CE];
    for (int e = 0; e < CE; e++) { ex[e] = __expf(logits[e] - m); s += ex[e]; }
    for (int e = 0; e < CE; e++) gates[b*CE + e] = ex[e] / s;
  }
}

__global__ __launch_bounds__(256) void k1b_qn(
    const float* __restrict__ xn, const float* __restrict__ g,
    const float* __restrict__ bln, float* __restrict__ qn) {
  int i = blockIdx.x*256 + threadIdx.x;      // flat [b][e][d], 65536
  int b = i >> 12, e = (i >> 9) & 7, d = i & 511;
  qn[i] = xn[b*CD + d] * g[e*CD + d] + bln[e*CD + d];
}

// Streaming split-K GEMV16: out_partial[kc][b][e][n] = sum_k X[b,e,k]*W[e,k,n]
template<int KC>
__global__ __launch_bounds__(256) void gstream(
    const float* __restrict__ X, int xb_, int xe_,
    const float* __restrict__ W, size_t we_, int ldw,
    float* __restrict__ P, int ntiles, size_t pc_, int pb_, int pe_) {
  int e = blockIdx.y;
  int nt = blockIdx.x % ntiles, kc = blockIdx.x / ntiles;
  int n0 = nt * 64, k0 = kc * KC;
  __shared__ float xs[KC][16];
  __shared__ float red[16][64];
  int t = threadIdx.x;
  for (int idx = t; idx < KC * 16; idx += 256) {
    int k = idx >> 4, b = idx & 15;
    xs[k][b] = X[(size_t)b * xb_ + (size_t)e * xe_ + k0 + k];
  }
  __syncthreads();
  int n = t & 63, kq = t >> 6;
  float acc[16] = {};
  const float* Wp = W + (size_t)e * we_ + (size_t)k0 * ldw + n0 + n;
  #pragma unroll 4
  for (int k = kq * (KC/4); k < (kq+1) * (KC/4); k++) {
    float w = Wp[(size_t)k * ldw];
    const float4* xp = reinterpret_cast<const float4*>(xs[k]);
    float4 x0 = xp[0], x1 = xp[1], x2 = xp[2], x3 = xp[3];
    acc[0]  += x0.x*w; acc[1]  += x0.y*w; acc[2]  += x0.z*w; acc[3]  += x0.w*w;
    acc[4]  += x1.x*w; acc[5]  += x1.y*w; acc[6]  += x1.z*w; acc[7]  += x1.w*w;
    acc[8]  += x2.x*w; acc[9]  += x2.y*w; acc[10] += x2.z*w; acc[11] += x2.w*w;
    acc[12] += x3.x*w; acc[13] += x3.y*w; acc[14] += x3.z*w; acc[15] += x3.w*w;
  }
  if (kq == 0) {
    #pragma unroll
    for (int b = 0; b < 16; b++) red[b][n] = acc[b];
  }
  __syncthreads();
  #pragma unroll
  for (int qq = 1; qq < 4; qq++) {
    if (kq == qq) {
      #pragma unroll
      for (int b = 0; b < 16; b++) red[b][n] += acc[b];
    }
    __syncthreads();
  }
  #pragma unroll
  for (int i = 0; i < 4; i++) {
    int b = kq*4 + i;
    P[(size_t)kc*pc_ + (size_t)b*pb_ + (size_t)e*pe_ + n0 + n] = red[b][n];
  }
}

// Wv variant: sums the 8 k6 partials during staging, then streams Wv column block.
__global__ __launch_bounds__(256) void gstream_v(
    const float* __restrict__ rp, const float* __restrict__ Wv,
    float* __restrict__ P) {
  int eh = blockIdx.y, kc = blockIdx.x;
  int e = eh >> 3, h = eh & 7;
  int k0 = kc * 64;
  __shared__ float xs[64][20];
  __shared__ float red[16][64];
  int t = threadIdx.x;
  for (int idx = t; idx < 64 * 16; idx += 256) {
    int k = idx & 63, b = idx >> 6;   // k fastest -> coalesced
    float s = 0.f;
    #pragma unroll
    for (int c = 0; c < 8; c++)
      s += rp[(size_t)c*(CB*CEH*CD) + ((size_t)(b*CEH + eh))*CD + k0 + k];
    xs[k][b] = s;
  }
  __syncthreads();
  int n = t & 63, kq = t >> 6;
  float acc[16] = {};
  const float* Wp = Wv + (size_t)e*CD*CD + (size_t)k0*CD + h*64 + n;
  #pragma unroll 4
  for (int k = kq*16; k < kq*16 + 16; k++) {
    float w = Wp[(size_t)k * CD];
    const float4* xp = reinterpret_cast<const float4*>(&xs[k][0]);
    float4 x0 = xp[0], x1 = xp[1], x2 = xp[2], x3 = xp[3];
    acc[0]  += x0.x*w; acc[1]  += x0.y*w; acc[2]  += x0.z*w; acc[3]  += x0.w*w;
    acc[4]  += x1.x*w; acc[5]  += x1.y*w; acc[6]  += x1.z*w; acc[7]  += x1.w*w;
    acc[8]  += x2.x*w; acc[9]  += x2.y*w; acc[10] += x2.z*w; acc[11] += x2.w*w;
    acc[12] += x3.x*w; acc[13] += x3.y*w; acc[14] += x3.z*w; acc[15] += x3.w*w;
  }
  if (kq == 0) { 
    #pragma unroll
    for (int b = 0; b < 16; b++) red[b][n] = acc[b]; }
  __syncthreads();
  #pragma unroll
  for (int qq = 1; qq < 4; qq++) {
    if (kq == qq) {
      #pragma unroll
      for (int b = 0; b < 16; b++) red[b][n] += acc[b];
    }
    __syncthreads();
  }
  #pragma unroll
  for (int i = 0; i < 4; i++) {
    int b = kq*4 + i;
    P[(size_t)kc*65536 + (size_t)b*4096 + (size_t)eh*64 + n] = red[b][n];
  }
}

__global__ __launch_bounds__(256) void comb8_bias(
    const float* __restrict__ P, const float* __restrict__ bias,
    float* __restrict__ out) {
  int i = blockIdx.x*256 + threadIdx.x;
  float s = bias[i & 4095];
  #pragma unroll
  for (int c = 0; c < 8; c++) s += P[(size_t)c*65536 + i];
  out[i] = s;
}

__global__ __launch_bounds__(256) void comb8_o(
    const float* __restrict__ P, const float* __restrict__ bias,
    const float* __restrict__ q, float* __restrict__ x) {
  int i = blockIdx.x*256 + threadIdx.x;
  float s = bias[i & 4095] + q[(i >> 12)*CD + (i & 511)];
  #pragma unroll
  for (int c = 0; c < 8; c++) s += P[(size_t)c*65536 + i];
  x[i] = s;
}

__global__ __launch_bounds__(256) void comb4_gelu(
    const float* __restrict__ P, const float* __restrict__ bias,
    float* __restrict__ out) {
  int i = blockIdx.x*256 + threadIdx.x;   // flat [b][e][f], 262144
  float s = bias[i & 16383];
  #pragma unroll
  for (int c = 0; c < 4; c++) s += P[(size_t)c*262144 + i];
  out[i] = 0.5f*s*(1.f + erff(s*0.70710678118f));
}

__global__ __launch_bounds__(256) void comb8_ffn2(
    const float* __restrict__ P, const float* __restrict__ bias,
    const float* __restrict__ x, float* __restrict__ yout) {
  int i = blockIdx.x*256 + threadIdx.x;
  float s = bias[i & 4095] + x[i];
  #pragma unroll
  for (int c = 0; c < 8; c++) s += P[(size_t)c*65536 + i];
  yout[i] = s;
}

__global__ __launch_bounds__(64) void k3_sbias(
    const float* __restrict__ qh, const float* __restrict__ bk,
    float* __restrict__ sbias) {
  int be = blockIdx.x, b = be >> 3, e = be & 7, t = threadIdx.x;
  for (int h = 0; h < CH; h++) {
    float v = qh[(b*CE + e)*CD + h*64 + t] * bk[e*CD + h*64 + t];
    for (int off = 32; off > 0; off >>= 1) v += __shfl_down(v, off);
    if (t == 0) sbias[(b*CE + e)*CH + h] = v;
  }
}

__global__ __launch_bounds__(256) void k4_wkeff(
    const float* __restrict__ Wk, const float* __restrict__ qh,
    __bf16* __restrict__ wkh) {
  int e = blockIdx.y;
  int h = blockIdx.x >> 3, dt = blockIdx.x & 7;
  int d0 = dt * 64;
  __shared__ float wks[64][65];   // [c][d]
  __shared__ float qs[64][16];    // [c][b]
  __shared__ float red[16][64];
  int t = threadIdx.x;
  for (int idx = t; idx < 64*64; idx += 256) {
    int c = idx & 63, d = idx >> 6;
    wks[c][d] = Wk[(size_t)e*CD*CD + (size_t)(d0+d)*CD + h*64 + c];
  }
  for (int idx = t; idx < 64*16; idx += 256) {
    int c = idx >> 4, b = idx & 15;
    qs[c][b] = qh[(b*CE + e)*CD + h*64 + c];
  }
  __syncthreads();
  int d = t & 63, cq = t >> 6;
  float acc[16] = {};
  #pragma unroll 4
  for (int c = cq*16; c < cq*16 + 16; c++) {
    float w = wks[c][d];
    const float4* xp = reinterpret_cast<const float4*>(qs[c]);
    float4 x0 = xp[0], x1 = xp[1], x2 = xp[2], x3 = xp[3];
    acc[0]  += x0.x*w; acc[1]  += x0.y*w; acc[2]  += x0.z*w; acc[3]  += x0.w*w;
    acc[4]  += x1.x*w; acc[5]  += x1.y*w; acc[6]  += x1.z*w; acc[7]  += x1.w*w;
    acc[8]  += x2.x*w; acc[9]  += x2.y*w; acc[10] += x2.z*w; acc[11] += x2.w*w;
    acc[12] += x3.x*w; acc[13] += x3.y*w; acc[14] += x3.z*w; acc[15] += x3.w*w;
  }
  if (cq == 0) { 
    #pragma unroll
    for (int b = 0; b < 16; b++) red[b][d] = acc[b]; }
  __syncthreads();
  #pragma unroll
  for (int qq = 1; qq < 4; qq++) {
    if (cq == qq) {
      #pragma unroll
      for (int b = 0; b < 16; b++) red[b][d] += acc[b];
    }
    __syncthreads();
  }
  int eh = e*8 + h;
  #pragma unroll
  for (int i = 0; i < 4; i++) {
    int b = cq*4 + i;
    wkh[((size_t)(b*CEH + eh))*CD + d0 + d] = (__bf16)red[b][d];
  }
}

// sc[b][eh][l] = (ret[b][l][:]·wk_eff[b][eh][:] + qh·bk)/8 via bf16 MFMA.
// Also emits per-16l-strip (max, expsum) for the row softmax.
__global__ __launch_bounds__(256) void k5_mfma(
    const float* __restrict__ ret, const __bf16* __restrict__ wkh,
    const float* __restrict__ sbias, float* __restrict__ sc,
    float* __restrict__ lmax, float* __restrict__ lsum) {
  int b = blockIdx.y, lt = blockIdx.x, t = threadIdx.x;
  int w = t >> 6, lane = t & 63;
  int lnlo = lane & 15, lnhi = lane >> 4;
  int l0 = lt*64 + w*16;
  f32x4 acc[4];
  #pragma unroll
  for (int et = 0; et < 4; et++) acc[et] = (f32x4){0.f,0.f,0.f,0.f};
  const float* retb = ret + ((size_t)(b*CL) + l0 + lnlo)*CD + lnhi*8;
  const __bf16* wb = wkh + (size_t)b*CEH*CD + (size_t)lnlo*CD + lnhi*8;
  for (int ks = 0; ks < 16; ks++) {
    int d = ks*32;
    float4 f0 = *reinterpret_cast<const float4*>(retb + d);
    float4 f1 = *reinterpret_cast<const float4*>(retb + d + 4);
    bf16x8 bfrag;
    bfrag[0]=(__bf16)f0.x; bfrag[1]=(__bf16)f0.y; bfrag[2]=(__bf16)f0.z; bfrag[3]=(__bf16)f0.w;
    bfrag[4]=(__bf16)f1.x; bfrag[5]=(__bf16)f1.y; bfrag[6]=(__bf16)f1.z; bfrag[7]=(__bf16)f1.w;
    #pragma unroll
    for (int et = 0; et < 4; et++) {
      bf16x8 afrag = *reinterpret_cast<const bf16x8*>(wb + (size_t)et*16*CD + d);
      acc[et] = __builtin_amdgcn_mfma_f32_16x16x32_bf16(afrag, bfrag, acc[et], 0, 0, 0);
    }
  }
  int strip = lt*4 + w;
  int l = l0 + lnlo;
  #pragma unroll
  for (int et = 0; et < 4; et++) {
    #pragma unroll
    for (int i = 0; i < 4; i++) {
      int eh = et*16 + lnhi*4 + i;
      float v = acc[et][i]*0.125f + sbias[b*CEH + eh]*0.125f;
      sc[((size_t)(b*CEH + eh))*CL + l] = v;
      float m = v;
      m = fmaxf(m, __shfl_xor(m, 1));
      m = fmaxf(m, __shfl_xor(m, 2));
      m = fmaxf(m, __shfl_xor(m, 4));
      m = fmaxf(m, __shfl_xor(m, 8));
      float s = __expf(v - m);
      s += __shfl_xor(s, 1);
      s += __shfl_xor(s, 2);
      s += __shfl_xor(s, 4);
      s += __shfl_xor(s, 8);
      if (lnlo == et*4 + i) {
        lmax[((size_t)(b*CEH + eh))*128 + strip] = m;
        lsum[((size_t)(b*CEH + eh))*128 + strip] = s;
      }
    }
  }
}

__global__ __launch_bounds__(256) void k5b2(
    const float* __restrict__ lmax, const float* __restrict__ lsum,
    float* __restrict__ rmax, float* __restrict__ rinv) {
  int b = blockIdx.x, t = threadIdx.x, eh = t & 63, q = t >> 6;
  const float* lm = lmax + ((size_t)(b*CEH + eh))*128 + q*32;
  const float* ls = lsum + ((size_t)(b*CEH + eh))*128 + q*32;
  float M = -1e30f, S = 0.f;
  for (int i = 0; i < 32; i++) {
    float m2 = lm[i], s2 = ls[i];
    float Mn = fmaxf(M, m2);
    S = S*__expf(M - Mn) + s2*__expf(m2 - Mn);
    M = Mn;
  }
  __shared__ float sm[4][64], ss[4][64];
  sm[q][eh] = M; ss[q][eh] = S;
  __syncthreads();
  if (q == 0) {
    #pragma unroll
    for (int i = 1; i < 4; i++) {
      float m2 = sm[i][eh], s2 = ss[i][eh];
      float Mn = fmaxf(M, m2);
      S = S*__expf(M - Mn) + s2*__expf(m2 - Mn);
      M = Mn;
    }
    rmax[b*CEH + eh] = M;
    rinv[b*CEH + eh] = 1.f / S;
  }
}

// normalize sc -> bf16 probs pb; entropy of head-averaged probs per (b,e)
__global__ __launch_bounds__(256) void k5n(
    const float* __restrict__ sc, const float* __restrict__ rmax,
    const float* __restrict__ rinv, __bf16* __restrict__ pb,
    float* __restrict__ entp) {
  int e = blockIdx.x, b = blockIdx.y, t = threadIdx.x;
  float M[8], inv[8];
  #pragma unroll
  for (int h = 0; h < 8; h++) {
    M[h] = rmax[b*CEH + e*8 + h];
    inv[h] = rinv[b*CEH + e*8 + h];
  }
  float ent = 0.f;
  for (int j = 0; j < 8; j++) {
    int l = j*256 + t;
    float pbav = 0.f;
    #pragma unroll
    for (int h = 0; h < 8; h++) {
      size_t ix = ((size_t)(b*CEH + e*8 + h))*CL + l;
      float p = __expf(sc[ix] - M[h]) * inv[h];
      pb[ix] = (__bf16)p;
      pbav += p;
    }
    pbav = fmaxf(pbav*0.125f, 1e-12f);
    ent -= pbav * __logf(pbav);
  }
  __shared__ float red[256];
  red[t] = ent; __syncthreads();
  for (int s = 128; s > 0; s >>= 1) { if (t < s) red[t] += red[t+s]; __syncthreads(); }
  if (t == 0) entp[b*CE + e] = red[0];
}

// reff partial[lc][b][eh][d] = sum_{l in chunk} P[b][eh][l] * ret[b][l][d] via bf16 MFMA.
// 8 d-tiles x 8 L-chunks per b; ping-pong LDS + register prefetch.
__global__ __launch_bounds__(256) void k6_mfma(
    const __bf16* __restrict__ pb, const float* __restrict__ ret,
    float* __restrict__ part) {
  int b = blockIdx.y;
  int dt = blockIdx.x & 7, lc = blockIdx.x >> 3;
  int d0 = dt*64, l0 = lc*256;
  int t = threadIdx.x, w = t >> 6, lane = t & 63;
  int lnlo = lane & 15, lnhi = lane >> 4;
  __shared__ __bf16 Bs[2][64][40];   // [buf][d][l] transposed ret tile
  f32x4 acc[4];
  #pragma unroll
  for (int et = 0; et < 4; et++) acc[et] = (f32x4){0.f,0.f,0.f,0.f};
  const __bf16* pbb = pb + ((size_t)(b*CEH) + lnlo)*CL + l0 + lnhi*8;
  int srow = t & 31, scol = (t >> 5)*8;
  const float* retb = ret + ((size_t)(b*CL) + l0 + srow)*CD + d0 + scol;
  // prefetch tile 0 (ret) and A-frags for kt=0
  float4 v0 = *reinterpret_cast<const float4*>(retb);
  float4 v1 = *reinterpret_cast<const float4*>(retb + 4);
  bf16x8 ap0 = *reinterpret_cast<const bf16x8*>(pbb);
  bf16x8 ap1 = *reinterpret_cast<const bf16x8*>(pbb + (size_t)16*CL);
  bf16x8 ap2 = *reinterpret_cast<const bf16x8*>(pbb + (size_t)32*CL);
  bf16x8 ap3 = *reinterpret_cast<const bf16x8*>(pbb + (size_t)48*CL);
  #pragma unroll
  for (int kt = 0; kt < 8; kt++) {
    int cur = kt & 1;
    Bs[cur][scol+0][srow] = (__bf16)v0.x; Bs[cur][scol+1][srow] = (__bf16)v0.y;
    Bs[cur][scol+2][srow] = (__bf16)v0.z; Bs[cur][scol+3][srow] = (__bf16)v0.w;
    Bs[cur][scol+4][srow] = (__bf16)v1.x; Bs[cur][scol+5][srow] = (__bf16)v1.y;
    Bs[cur][scol+6][srow] = (__bf16)v1.z; Bs[cur][scol+7][srow] = (__bf16)v1.w;
    bf16x8 an0, an1, an2, an3;
    if (kt < 7) {
      v0 = *reinterpret_cast<const float4*>(retb + (size_t)(kt+1)*32*CD);
      v1 = *reinterpret_cast<const float4*>(retb + (size_t)(kt+1)*32*CD + 4);
      an0 = *reinterpret_cast<const bf16x8*>(pbb + (kt+1)*32);
      an1 = *reinterpret_cast<const bf16x8*>(pbb + (size_t)16*CL + (kt+1)*32);
      an2 = *reinterpret_cast<const bf16x8*>(pbb + (size_t)32*CL + (kt+1)*32);
      an3 = *reinterpret_cast<const bf16x8*>(pbb + (size_t)48*CL + (kt+1)*32);
    }
    __syncthreads();
    bf16x8 bfrag = *reinterpret_cast<const bf16x8*>(&Bs[cur][w*16 + lnlo][lnhi*8]);
    acc[0] = __builtin_amdgcn_mfma_f32_16x16x32_bf16(ap0, bfrag, acc[0], 0, 0, 0);
    acc[1] = __builtin_amdgcn_mfma_f32_16x16x32_bf16(ap1, bfrag, acc[1], 0, 0, 0);
    acc[2] = __builtin_amdgcn_mfma_f32_16x16x32_bf16(ap2, bfrag, acc[2], 0, 0, 0);
    acc[3] = __builtin_amdgcn_mfma_f32_16x16x32_bf16(ap3, bfrag, acc[3], 0, 0, 0);
    if (kt < 7) { ap0 = an0; ap1 = an1; ap2 = an2; ap3 = an3; }
  }
  float* dst = part + (size_t)lc*(CB*CEH*CD);
  int d = d0 + w*16 + lnlo;
  #pragma unroll
  for (int et = 0; et < 4; et++) {
    #pragma unroll
    for (int i = 0; i < 4; i++) {
      int eh = et*16 + lnhi*4 + i;
      dst[((size_t)(b*CEH + eh))*CD + d] = acc[et][i];
    }
  }
}

__global__ __launch_bounds__(256) void k7_lno(
    const float* __restrict__ x, const float* __restrict__ g,
    const float* __restrict__ bb, float* __restrict__ xo) {
  int be = blockIdx.x, e = be & 7, t = threadIdx.x;
  __shared__ float red[256];
  const float* xr = x + (size_t)be*CD;
  float v0 = xr[t], v1 = xr[256 + t];
  red[t] = v0 + v1; __syncthreads();
  for (int s = 128; s > 0; s >>= 1) { if (t < s) red[t] += red[t+s]; __syncthreads(); }
  float mu = red[0] * (1.0f/CD); __syncthreads();
  float c0 = v0 - mu, c1 = v1 - mu;
  red[t] = c0*c0 + c1*c1; __syncthreads();
  for (int s = 128; s > 0; s >>= 1) { if (t < s) red[t] += red[t+s]; __syncthreads(); }
  float rstd = rsqrtf(red[0] * (1.0f/CD) + 1e-5f);
  xo[be*CD + t]       = c0*rstd*g[e*CD + t]       + bb[e*CD + t];
  xo[be*CD + 256 + t] = c1*rstd*g[e*CD + 256 + t] + bb[e*CD + 256 + t];
}

__global__ __launch_bounds__(512) void k10_final(
    const float* __restrict__ gates, const float* __restrict__ entp,
    const float* __restrict__ yout, float* __restrict__ fused,
    float* __restrict__ gtout) {
  int b = blockIdx.x, t = threadIdx.x;
  __shared__ float gt_s[CE];
  if (t < CE) {
    gt_s[t] = gates[b*CE + t] * __expf(-0.5f * entp[b*CE + t]);
  }
  __syncthreads();
  if (t == 0) {
    float s = 0.f;
    for (int e = 0; e < CE; e++) s += gt_s[e];
    s += 1e-9f;
    for (int e = 0; e < CE; e++) { gt_s[e] /= s; gtout[b*CE + e] = gt_s[e]; }
  }
  __syncthreads();
  float acc = 0.f;
  #pragma unroll
  for (int e = 0; e < CE; e++) acc += gt_s[e] * yout[(b*CE + e)*CD + t];
  fused[b*CD + t] = acc;  // ALPHA = 1.0 -> fused == mixture
}

extern "C" void kernel_launch(void* const* d_in, const int* in_sizes, int n_in,
                              void* d_out, int out_size, void* d_ws, size_t ws_size,
                              hipStream_t stream) {
  const float* q    = (const float*)d_in[0];
  const float* ret  = (const float*)d_in[1];
  const float* wg   = (const float*)d_in[2];
  const float* lnqg = (const float*)d_in[3];
  const float* lnqb = (const float*)d_in[4];
  const float* Wq   = (const float*)d_in[5];
  const float* bq   = (const float*)d_in[6];
  const float* Wk   = (const float*)d_in[7];
  const float* bk   = (const float*)d_in[8];
  const float* Wv   = (const float*)d_in[9];
  const float* bv   = (const float*)d_in[10];
  const float* Wo   = (const float*)d_in[11];
  const float* bo   = (const float*)d_in[12];
  const float* lnog = (const float*)d_in[13];
  const float* lnob = (const float*)d_in[14];
  const float* W1   = (const float*)d_in[15];
  const float* b1   = (const float*)d_in[16];
  const float* W2   = (const float*)d_in[17];
  const float* b2   = (const float*)d_in[18];

  float* ws = (float*)d_ws;
  float* fused = (float*)d_out;
  float* yout  = fused + CB*CD;
  float* gtout = yout + CB*CE*CD;

  float* gates = ws + WS_GATES;
  float* xn    = ws + WS_XN;
  float* qn    = ws + WS_QN;
  float* qh    = ws + WS_QH;
  float* sbias = ws + WS_SBIAS;
  __bf16* wkh  = (__bf16*)(ws + WS_WK);
  float* sc    = ws + WS_SC;
  float* part  = ws + WS_PART;
  float* rmax  = ws + WS_RMAX;
  float* rinv  = ws + WS_RINV;
  float* entp  = ws + WS_ENT;
  float* attn  = ws + WS_ATTN;
  float* xb    = ws + WS_X;
  float* xo    = ws + WS_XO;
  float* hbuf  = ws + WS_HB;
  float* rpart = ws + WS_RP;
  __bf16* pb16 = (__bf16*)(ws + WS_PB16);
  float* lmax  = rpart;                      // dead before k6_mfma writes rpart
  float* lsum  = rpart + CB*CEH*128;

  k1_gates_xn<<<CB, 256, 0, stream>>>(q, wg, xn, gates);
  k1b_qn<<<256, 256, 0, stream>>>(xn, lnqg, lnqb, qn);
  // qh = qn @ Wq + bq : K=512 (8 chunks of 64), N=512 (8 tiles)
  gstream<64><<<dim3(64, CE), 256, 0, stream>>>(qn, CE*CD, CD, Wq, (size_t)CD*CD, CD,
                                                part, 8, 65536, CE*CD, CD);
  comb8_bias<<<256, 256, 0, stream>>>(part, bq, qh);
  k3_sbias<<<CB*CE, 64, 0, stream>>>(qh, bk, sbias);
  k4_wkeff<<<dim3(64, CE), 256, 0, stream>>>(Wk, qh, wkh);
  k5_mfma<<<dim3(32, CB), 256, 0, stream>>>(ret, wkh, sbias, sc, lmax, lsum);
  k5b2<<<CB, 256, 0, stream>>>(lmax, lsum, rmax, rinv);
  k5n<<<dim3(CE, CB), 256, 0, stream>>>(sc, rmax, rinv, pb16, entp);
  k6_mfma<<<dim3(64, CB), 256, 0, stream>>>(pb16, ret, rpart);
  // attn = reff @ Wv + bv : per (e,h), K=512 (8 chunks); reff summed from rpart inside
  gstream_v<<<dim3(8, CEH), 256, 0, stream>>>(rpart, Wv, part);
  comb8_bias<<<256, 256, 0, stream>>>(part, bv, attn);
  // x = q + attn @ Wo + bo
  gstream<64><<<dim3(64, CE), 256, 0, stream>>>(attn, CE*CD, CD, Wo, (size_t)CD*CD, CD,
                                                part, 8, 65536, CE*CD, CD);
  comb8_o<<<256, 256, 0, stream>>>(part, bo, q, xb);
  k7_lno<<<CB*CE, 256, 0, stream>>>(xb, lnog, lnob, xo);
  // h = gelu(xo @ W1 + b1) : K=512 (4 chunks of 128), N=2048 (32 tiles)
  gstream<128><<<dim3(128, CE), 256, 0, stream>>>(xo, CE*CD, CD, W1, (size_t)CD*CF, CF,
                                                  part, 32, 262144, CE*CF, CF);
  comb4_gelu<<<1024, 256, 0, stream>>>(part, b1, hbuf);
  // y = h @ W2 + b2 + x : K=2048 (8 chunks of 256), N=512 (8 tiles)
  gstream<256><<<dim3(64, CE), 256, 0, stream>>>(hbuf, CE*CF, CF, W2, (size_t)CF*CD, CD,
                                                 part, 8, 65536, CE*CD, CD);
  comb8_ffn2<<<256, 256, 0, stream>>>(part, b2, xb, yout);
  k10_final<<<CB, 512, 0, stream>>>(gates, entp, yout, fused, gtout);
}